// Round 4
// baseline (334.167 us; speedup 1.0000x reference)
//
#include <hip/hip_runtime.h>
#include <hip/hip_bf16.h>
#include <math.h>

// Problem constants
#define BB 4
#define TT 2048
#define CC 1024
#define NH 16
#define HD 64
#define C3 3072
#define LDK 72   // padded LDS row stride (bf16 elems) - vtranspose only

// exp2-domain query scale: 0.125 * log2(e)
#define QSCALE 0.18033688011112042f

typedef __attribute__((ext_vector_type(8))) short bf16x8;
typedef __attribute__((ext_vector_type(4))) float f32x4;

// async global->LDS, 16 B per lane; LDS dest = wave-uniform base + lane*16
__device__ __forceinline__ void gload_lds16(const __hip_bfloat16* g, __hip_bfloat16* s) {
    __builtin_amdgcn_global_load_lds((const __attribute__((address_space(1))) void*)g,
                                     (__attribute__((address_space(3))) void*)s, 16, 0, 0);
}

// ---------------------------------------------------------------------------
// RoPE tables: tab[t*32 + p] = (cos, sin); the only sincosf call site.
// ---------------------------------------------------------------------------
__global__ __launch_bounds__(256) void rope_tables(float2* __restrict__ tab) {
    int idx = blockIdx.x * 256 + threadIdx.x;   // 0..65535
    int t = idx >> 5;
    int p = idx & 31;
    float invf = exp2f((float)p * (-13.287712379549449f / 32.0f));  // 10000^(-p/32)
    float ang = (float)t * invf;
    float s, c;
    sincosf(ang, &s, &c);
    tab[idx] = make_float2(c, s);
}

// ---------------------------------------------------------------------------
// cast fp32 -> bf16, 8 elements/thread
// ---------------------------------------------------------------------------
__global__ __launch_bounds__(256) void cast_bf16x8(const float* __restrict__ X,
                                                   __hip_bfloat16* __restrict__ Y) {
    size_t i = ((size_t)blockIdx.x * 256 + threadIdx.x) * 8;
    float4 a = *(const float4*)(X + i);
    float4 b = *(const float4*)(X + i + 4);
    __align__(16) __hip_bfloat16 tmp[8];
    tmp[0] = __float2bfloat16(a.x);
    tmp[1] = __float2bfloat16(a.y);
    tmp[2] = __float2bfloat16(a.z);
    tmp[3] = __float2bfloat16(a.w);
    tmp[4] = __float2bfloat16(b.x);
    tmp[5] = __float2bfloat16(b.y);
    tmp[6] = __float2bfloat16(b.z);
    tmp[7] = __float2bfloat16(b.w);
    *(bf16x8*)(Y + i) = *(bf16x8*)tmp;
}

// ---------------------------------------------------------------------------
// W[K][N] fp32  ->  Wt[N][K] bf16   (64x64 tiles via LDS)
// ---------------------------------------------------------------------------
__global__ __launch_bounds__(256) void wtrans(const float* __restrict__ W,
                                              __hip_bfloat16* __restrict__ Wt,
                                              int K, int N) {
    __shared__ float st[64][65];
    const int n0 = blockIdx.x * 64;
    const int k0 = blockIdx.y * 64;
    const int tid = threadIdx.x;
    const int r = tid >> 4;
    const int c4 = (tid & 15) * 4;
#pragma unroll
    for (int p = 0; p < 4; ++p) {
        int k = p * 16 + r;
        float4 v = *(const float4*)(W + (size_t)(k0 + k) * N + n0 + c4);
        st[c4 + 0][k] = v.x;
        st[c4 + 1][k] = v.y;
        st[c4 + 2][k] = v.z;
        st[c4 + 3][k] = v.w;
    }
    __syncthreads();
    const int rr = tid >> 3;
    const int cc = (tid & 7) * 8;
#pragma unroll
    for (int p = 0; p < 2; ++p) {
        int n = p * 32 + rr;
        __align__(16) __hip_bfloat16 tmp[8];
#pragma unroll
        for (int j = 0; j < 8; ++j) tmp[j] = __float2bfloat16(st[n][cc + j]);
        *(bf16x8*)(Wt + (size_t)(n0 + n) * K + k0 + cc) = *(bf16x8*)tmp;
    }
}

// ---------------------------------------------------------------------------
// 256x256 8-phase GEMM (T2 st_16x32 swizzle + T3/T4 counted vmcnt + T5 setprio)
// (unchanged — verified in rounds 1-3)
// ---------------------------------------------------------------------------
#define CA0 0
#define CA1 1
#define CB0 2
#define CB1 3

#define BAR() __builtin_amdgcn_s_barrier()
#define SB0() __builtin_amdgcn_sched_barrier(0)
#define WAIT_LGKM0() do { asm volatile("s_waitcnt lgkmcnt(0)" ::: "memory"); SB0(); } while (0)
#define WAIT_VM4()   do { asm volatile("s_waitcnt vmcnt(4)" ::: "memory");  SB0(); } while (0)

#define CLAMP_TS(x) ((x) < NTILE ? (x) : (x) - 2)

// wave w stages subtile-row w (16 rows) of the chunk: 2 x 1KiB wave-calls
#define STAGE(gbase, h, ts, buf, cid) do {                                            \
    const __hip_bfloat16* _s = (gbase) + (size_t)((h) * 128 + w * 16) * K + (ts) * 64; \
    __hip_bfloat16* _d = &lds[buf][cid][w * 1024];                                    \
    gload_lds16(_s, _d);                                                              \
    gload_lds16(_s + 32, _d + 512);                                                   \
} while (0)

#define FRAGP(buf, cid, rowsub, ks)                                                   \
    ((const bf16x8*)((const char*)&lds[buf][cid][0] +                                 \
        (((rowsub) * 2 + (ks)) << 10) + (l16 << 6) + swzoff))

#define READ_A(buf, mi) do {                                                          \
    _Pragma("unroll") for (int _m = 0; _m < 4; ++_m)                                  \
    _Pragma("unroll") for (int _k = 0; _k < 2; ++_k)                                  \
        af[_m][_k] = *FRAGP(buf, wm, (mi) * 4 + _m, _k);                              \
} while (0)

#define READ_B(buf, ni) do {                                                          \
    _Pragma("unroll") for (int _n = 0; _n < 2; ++_n)                                  \
    _Pragma("unroll") for (int _k = 0; _k < 2; ++_k)                                  \
        bfr[(ni) * 2 + _n][_k] =                                                      \
            *FRAGP(buf, 2 + (wn >> 1), (wn & 1) * 4 + (ni) * 2 + _n, _k);             \
} while (0)

#define MFMA_Q(mb, nb) do {                                                           \
    __builtin_amdgcn_s_setprio(1);                                                    \
    _Pragma("unroll") for (int _m = 0; _m < 4; ++_m)                                  \
    _Pragma("unroll") for (int _n = 0; _n < 2; ++_n)                                  \
    _Pragma("unroll") for (int _k = 0; _k < 2; ++_k)                                  \
        acc[(mb) * 4 + _m][(nb) * 2 + _n] = __builtin_amdgcn_mfma_f32_16x16x32_bf16(  \
            af[_m][_k], bfr[(nb) * 2 + _n][_k], acc[(mb) * 4 + _m][(nb) * 2 + _n],    \
            0, 0, 0);                                                                 \
    __builtin_amdgcn_s_setprio(0);                                                    \
} while (0)

#define HALF_ITER(BUF, T12, B12, T34, B34) do {                                       \
    /* phase A: Q(0,0) */                                                             \
    READ_A(BUF, 0);                                                                   \
    READ_B(BUF, 0);                                                                   \
    STAGE(Bb, 1, CLAMP_TS(T12), B12, CB1);                                            \
    BAR(); WAIT_LGKM0();                                                              \
    MFMA_Q(0, 0);                                                                     \
    BAR();                                                                            \
    /* phase B: Q(0,1) */                                                             \
    READ_B(BUF, 1);                                                                   \
    STAGE(Ab, 1, CLAMP_TS(T12), B12, CA1);                                            \
    BAR(); WAIT_LGKM0();                                                              \
    MFMA_Q(0, 1);                                                                     \
    BAR();                                                                            \
    /* phase C: Q(1,0) */                                                             \
    READ_A(BUF, 1);                                                                   \
    STAGE(Bb, 0, CLAMP_TS(T34), B34, CB0);                                            \
    BAR(); WAIT_LGKM0();                                                              \
    MFMA_Q(1, 0);                                                                     \
    BAR();                                                                            \
    /* phase D: Q(1,1) */                                                             \
    STAGE(Ab, 0, CLAMP_TS(T34), B34, CA0);                                            \
    BAR(); WAIT_LGKM0();                                                              \
    MFMA_Q(1, 1);                                                                     \
    WAIT_VM4();                                                                       \
    BAR(); SB0();                                                                     \
} while (0)

#define GEMM256_BODY                                                                  \
    __shared__ __align__(16) __hip_bfloat16 lds[2][4][8192]; /* 128 KiB */            \
    const int tid = threadIdx.x;                                                      \
    const int w = tid >> 6;                                                           \
    const int lane = tid & 63;                                                        \
    const int l16 = lane & 15;                                                        \
    const int quad = lane >> 4;                                                       \
    const int wm = w >> 2;                                                            \
    const int wn = w & 3;                                                             \
    const int swzoff = ((quad * 8) ^ ((l16 & 8) << 1)) << 1;                          \
    const int bm0 = blockIdx.y * 256;                                                 \
    const int bn0 = blockIdx.x * 256;                                                 \
    const int NTILE = K >> 6;                                                         \
    const size_t laneOff = (size_t)(lane >> 2) * K +                                  \
                           (((lane & 3) * 8) ^ ((lane >> 5) << 4));                   \
    const __hip_bfloat16* Ab = A + (size_t)bm0 * K + laneOff;                         \
    const __hip_bfloat16* Bb = Bt + (size_t)bn0 * K + laneOff;                        \
    f32x4 acc[8][4] = {};                                                             \
    /* prologue: tile0 fully + tile1's CB0/CA0 (matches steady chronology) */         \
    STAGE(Bb, 0, 0, 0, CB0);                                                          \
    STAGE(Ab, 0, 0, 0, CA0);                                                          \
    STAGE(Bb, 1, 0, 0, CB1);                                                          \
    STAGE(Ab, 1, 0, 0, CA1);                                                          \
    STAGE(Bb, 0, 1, 1, CB0);                                                          \
    STAGE(Ab, 0, 1, 1, CA0);                                                          \
    WAIT_VM4();                                                                       \
    BAR(); SB0();                                                                     \
    for (int it = 0; it < NTILE / 2; ++it) {                                          \
        const int t = it * 2;                                                         \
        bf16x8 af[4][2], bfr[4][2];                                                   \
        HALF_ITER(0, t + 1, 1, t + 2, 0);                                             \
        HALF_ITER(1, t + 2, 0, t + 3, 1);                                             \
    }

// ---------------------------------------------------------------------------
// qkv = x @ W_attn with fused interleaved RoPE epilogue (8-phase 256^2 core)
// ---------------------------------------------------------------------------
__global__ __launch_bounds__(512) void gemm256_qkv_rope(const __hip_bfloat16* __restrict__ A,
                                                        const __hip_bfloat16* __restrict__ Bt,
                                                        const float2* __restrict__ tab,
                                                        __hip_bfloat16* __restrict__ C,
                                                        int M, int N, int K) {
    GEMM256_BODY

    if (bn0 < 2048) {
        const float qsc = (bn0 < 1024) ? QSCALE : 1.0f;
        const float sgn = (l16 & 1) ? 1.0f : -1.0f;
#pragma unroll
        for (int mt = 0; mt < 8; ++mt) {
            int row = bm0 + wm * 128 + mt * 16 + quad * 4;
#pragma unroll
            for (int nt = 0; nt < 4; ++nt) {
                int col = bn0 + wn * 64 + nt * 16 + l16;
                int p2 = nt * 8 + (l16 >> 1);
#pragma unroll
                for (int r = 0; r < 4; ++r) {
                    float own = acc[mt][nt][r];
                    float part = __shfl_xor(own, 1);
                    int trow = (row + r) & (TT - 1);
                    float2 cs = tab[(trow << 5) + p2];
                    float res = (own * cs.x + sgn * part * cs.y) * qsc;
                    C[(size_t)(row + r) * N + col] = __float2bfloat16(res);
                }
            }
        }
    } else {
#pragma unroll
        for (int mt = 0; mt < 8; ++mt) {
            int row = bm0 + wm * 128 + mt * 16 + quad * 4;
#pragma unroll
            for (int nt = 0; nt < 4; ++nt) {
                int col = bn0 + wn * 64 + nt * 16 + l16;
#pragma unroll
                for (int r = 0; r < 4; ++r)
                    C[(size_t)(row + r) * N + col] = __float2bfloat16(acc[mt][nt][r]);
            }
        }
    }
}

// ---------------------------------------------------------------------------
// out-proj GEMM, fp32 store (8-phase 256^2 core)
// ---------------------------------------------------------------------------
__global__ __launch_bounds__(512) void gemm256_f32(const __hip_bfloat16* __restrict__ A,
                                                   const __hip_bfloat16* __restrict__ Bt,
                                                   float* __restrict__ C,
                                                   int M, int N, int K) {
    GEMM256_BODY
#pragma unroll
    for (int mt = 0; mt < 8; ++mt) {
        int row = bm0 + wm * 128 + mt * 16 + quad * 4;
#pragma unroll
        for (int nt = 0; nt < 4; ++nt) {
            int col = bn0 + wn * 64 + nt * 16 + l16;
#pragma unroll
            for (int r = 0; r < 4; ++r)
                C[(size_t)(row + r) * N + col] = acc[mt][nt][r];
        }
    }
}

// ---------------------------------------------------------------------------
// V transpose + K repack:
//   V: qkvb[b][t][2C + h*64 + d] -> vtb[(b*16+h)*64 + d][t]      (via LDS)
//   K: qkvb[b][t][ C + h*64 + d] -> ktb[((b*16+h)*2048 + t)*64 + d]  (copy)
// ktb gives attention contiguous 128-B K rows per head -> coalesced direct
// global fragment reads (no LDS staging needed in attn).
// ---------------------------------------------------------------------------
__global__ __launch_bounds__(256) void vktranspose(const __hip_bfloat16* __restrict__ qkvb,
                                                   __hip_bfloat16* __restrict__ vtb,
                                                   __hip_bfloat16* __restrict__ ktb) {
    __shared__ __align__(16) __hip_bfloat16 st[64][LDK];
    const int bh = blockIdx.x >> 5;
    const int tt = blockIdx.x & 31;
    const int b = bh >> 4;
    const int h = bh & 15;
    const int tid = threadIdx.x;
    const int row = tid >> 3;
    const int col8 = (tid & 7) * 8;

#pragma unroll
    for (int pass = 0; pass < 2; ++pass) {
        int t = pass * 32 + row;
        const __hip_bfloat16* src = qkvb + ((size_t)(b * TT + tt * 64 + t)) * C3 + h * HD + col8;
        *(bf16x8*)(&st[t][col8]) = *(const bf16x8*)(src + 2 * CC);   // V -> LDS
        // K pass-through repack (contiguous per-head rows)
        *(bf16x8*)(ktb + ((size_t)(bh * TT + tt * 64 + t)) * HD + col8) =
            *(const bf16x8*)(src + CC);
    }
    __syncthreads();
#pragma unroll
    for (int pass = 0; pass < 2; ++pass) {
        int d = pass * 32 + row;
        __align__(16) __hip_bfloat16 tmp[8];
#pragma unroll
        for (int j = 0; j < 8; ++j) tmp[j] = st[col8 + j][d];
        *(bf16x8*)(vtb + ((size_t)bh * HD + d) * TT + tt * 64 + col8) = *(bf16x8*)tmp;
    }
}

// ---------------------------------------------------------------------------
// MFMA flash attention v8 (causal): same math as verified v5/v6 (S^T form,
// fixed-max exp2 softmax), but ZERO-BARRIER direct-L2 structure:
//   - 2048 blocks x 64 threads (1 wave). No __syncthreads, no vmcnt asm.
//   - K fragments read directly from ktb (128-B rows/head: a wave's kf load
//     = 16 aligned 64-B lines, 4 lanes/line). V fragments directly from vtb
//     (same pattern). K+V per bh = 512 KB; XCD-chunked remap puts the 32
//     blocks of each bh on one XCD (8 bh x 512 KB = 4 MB = one L2).
//   - per-wave exact causal range: unit u covers q-rows [32u, 32u+32),
//     jtmax = (32u+31)>>6; pairing u with 63-u gives uniform 33 tiles/block.
//   - Ps (P bf16 repack) per-wave in LDS (2.3 KB); within-wave lgkmcnt
//     ordering only.
//   - 16 independent global loads clustered per iteration -> one L2 round
//     trip; latency hidden by 8 independent waves/CU.
// ---------------------------------------------------------------------------
__global__ __launch_bounds__(64, 2) void attn_mfma8(const __hip_bfloat16* __restrict__ qkvb,
                                                    const __hip_bfloat16* __restrict__ ktb,
                                                    const __hip_bfloat16* __restrict__ vtb,
                                                    __hip_bfloat16* __restrict__ y) {
    __shared__ __align__(16) __hip_bfloat16 Ps[16 * 72];

    const int lane = threadIdx.x;
    const int l16 = lane & 15;
    const int quad = lane >> 4;

    const int rb = blockIdx.x;
    const int lb = (rb & 7) * 256 + (rb >> 3);   // XCD-chunked bijective remap (2048 = 8*256)
    const int bh = lb >> 5;                      // 0..63
    const int u  = lb & 31;                      // 0..31
    const int b = bh >> 4;
    const int h = bh & 15;

    const __hip_bfloat16* kb = ktb + (size_t)bh * TT * HD;
    const __hip_bfloat16* vb = vtb + (size_t)bh * HD * TT;

#pragma unroll
    for (int seg = 0; seg < 2; ++seg) {
        const int unit = seg ? (63 - u) : u;
        const int qn0 = unit * 32;
        const int qn1 = qn0 + 16;
        const int jtmax = (qn0 + 31) >> 6;

        // Q B-frags (B[k=dim][n=query]), rope'd + exp2-scaled already
        bf16x8 qf[2][2];
#pragma unroll
        for (int qt = 0; qt < 2; ++qt) {
            const __hip_bfloat16* qp = qkvb + (size_t)(b * TT + qn0 + qt * 16 + l16) * C3 + h * HD;
            qf[qt][0] = *(const bf16x8*)(qp + quad * 8);
            qf[qt][1] = *(const bf16x8*)(qp + 32 + quad * 8);
        }

        f32x4 O[2][4] = {};
        float l_q[2] = {0.f, 0.f};               // per-quad partial; reduced in epilogue

        for (int jt = 0; jt <= jtmax; ++jt) {
            const __hip_bfloat16* kt = kb + (size_t)jt * 64 * HD;
            const __hip_bfloat16* vt = vb + jt * 64;

            // ---- all 16 fragment loads upfront (independent; one L2 trip) ----
            bf16x8 kf[2][4];
#pragma unroll
            for (int ks = 0; ks < 2; ++ks)
#pragma unroll
                for (int mt = 0; mt < 4; ++mt)
                    kf[ks][mt] = *(const bf16x8*)(kt + (size_t)(mt * 16 + l16) * HD +
                                                  (ks * 4 + quad) * 8);
            bf16x8 vf[4][2];
#pragma unroll
            for (int dt = 0; dt < 4; ++dt) {
                const __hip_bfloat16* vr = vt + (size_t)(dt * 16 + l16) * TT;
                vf[dt][0] = *(const bf16x8*)(vr + quad * 8);
                vf[dt][1] = *(const bf16x8*)(vr + 32 + quad * 8);
            }

            // ---- S^T = K * Q^T (exp2 domain, zero-init) ----
            f32x4 St[2][4] = {};
            __builtin_amdgcn_s_setprio(1);
#pragma unroll
            for (int ks = 0; ks < 2; ++ks) {
#pragma unroll
                for (int mt = 0; mt < 4; ++mt) {
                    St[0][mt] = __builtin_amdgcn_mfma_f32_16x16x32_bf16(kf[ks][mt], qf[0][ks], St[0][mt], 0, 0, 0);
                    St[1][mt] = __builtin_amdgcn_mfma_f32_16x16x32_bf16(kf[ks][mt], qf[1][ks], St[1][mt], 0, 0, 0);
                }
            }
            __builtin_amdgcn_s_setprio(0);

            const bool sk0 = (jt * 64 > qn0 + 15);   // qt0 fully above diagonal (last tile only)

            // ---- per-qtile sequential: mask, exp2, pack P, PV ----
#pragma unroll
            for (int qt = 0; qt < 2; ++qt) {
                if (qt == 0 && sk0) continue;
                const int qn = qt == 0 ? qn0 : qn1;
                if (jt * 64 + 63 > qn) {             // diagonal tile: causal mask
#pragma unroll
                    for (int mt = 0; mt < 4; ++mt) {
#pragma unroll
                        for (int r = 0; r < 4; ++r) {
                            int key = jt * 64 + mt * 16 + quad * 4 + r;
                            if (key > qn + l16) St[qt][mt][r] = -__builtin_inff();
                        }
                    }
                }
                float sum = 0.f;
#pragma unroll
                for (int mt = 0; mt < 4; ++mt) {
                    float e0 = exp2f(St[qt][mt][0]);
                    float e1 = exp2f(St[qt][mt][1]);
                    float e2 = exp2f(St[qt][mt][2]);
                    float e3 = exp2f(St[qt][mt][3]);
                    sum += (e0 + e1) + (e2 + e3);
                    union { uint2 uu; __hip_bfloat162 hh[2]; } up;
                    up.hh[0] = __float22bfloat162_rn(make_float2(e0, e1));
                    up.hh[1] = __float22bfloat162_rn(make_float2(e2, e3));
                    *(uint2*)(&Ps[l16 * 72 + mt * 16 + quad * 4]) = up.uu;
                }
                l_q[qt] += sum;

                bf16x8 pa0 = *(const bf16x8*)(&Ps[l16 * 72 + quad * 8]);
                bf16x8 pa1 = *(const bf16x8*)(&Ps[l16 * 72 + 32 + quad * 8]);
                __builtin_amdgcn_s_setprio(1);
#pragma unroll
                for (int dt = 0; dt < 4; ++dt) {
                    O[qt][dt] = __builtin_amdgcn_mfma_f32_16x16x32_bf16(pa0, vf[dt][0], O[qt][dt], 0, 0, 0);
                    O[qt][dt] = __builtin_amdgcn_mfma_f32_16x16x32_bf16(pa1, vf[dt][1], O[qt][dt], 0, 0, 0);
                }
                __builtin_amdgcn_s_setprio(0);
            }
        }

        // ---- epilogue: reduce l across quads, normalize, store ----
#pragma unroll
        for (int qt = 0; qt < 2; ++qt) {
            float l2 = l_q[qt];
            l2 += __shfl_xor(l2, 16);
            l2 += __shfl_xor(l2, 32);
            float lO[4];
#pragma unroll
            for (int r = 0; r < 4; ++r) lO[r] = 1.0f / __shfl(l2, quad * 4 + r);
            const int qbase = qn0 + qt * 16 + quad * 4;
#pragma unroll
            for (int dt = 0; dt < 4; ++dt) {
#pragma unroll
                for (int r = 0; r < 4; ++r) {
                    y[(size_t)(b * TT + qbase + r) * CC + h * HD + dt * 16 + l16] =
                        __float2bfloat16(O[qt][dt][r] * lO[r]);
                }
            }
        }
    }
}

// ---------------------------------------------------------------------------
extern "C" void kernel_launch(void* const* d_in, const int* in_sizes, int n_in,
                              void* d_out, int out_size, void* d_ws, size_t ws_size,
                              hipStream_t stream) {
    const float* x      = (const float*)d_in[0];   // (B,T,C)
    const float* W_attn = (const float*)d_in[1];   // (C, 3C)
    const float* W_proj = (const float*)d_in[2];   // (C, C)
    float* out = (float*)d_out;                    // (B,T,C)

    const size_t NBT = (size_t)BB * TT;            // 8192
    // Workspace layout (98 MB). ktb overlaps Wab/tab: lifetimes are disjoint
    // (Wab/tab consumed by the qkv GEMM before vktranspose writes ktb).
    __hip_bfloat16* xb   = (__hip_bfloat16*)d_ws;            // B*T*C (reused as yb)
    __hip_bfloat16* qkvb = xb + NBT * CC;                    // B*T*3C
    __hip_bfloat16* vtb  = qkvb + NBT * C3;                  // B*H*64*T
    __hip_bfloat16* ktb  = vtb + NBT * CC;                   // B*H*T*64 (after qkv GEMM)
    __hip_bfloat16* Wab  = ktb;                              // 3C*C [N][K]  (dead before ktb)
    float2* tab          = (float2*)(Wab + (size_t)CC * C3); // T*32 float2  (dead before ktb)
    __hip_bfloat16* Wpb  = ktb + NBT * CC;                   // C*C  [N][K]  (persistent)
    __hip_bfloat16* yb   = xb;                               // reuse after qkv GEMM

    const int M = BB * TT;   // 8192

    rope_tables<<<dim3(TT * 32 / 256), 256, 0, stream>>>(tab);
    cast_bf16x8<<<dim3((int)(NBT * CC / 2048)), 256, 0, stream>>>(x, xb);
    wtrans<<<dim3(C3 / 64, CC / 64), 256, 0, stream>>>(W_attn, Wab, CC, C3);
    wtrans<<<dim3(CC / 64, CC / 64), 256, 0, stream>>>(W_proj, Wpb, CC, CC);

    // 1) qkv = x @ W_attn with fused table-RoPE epilogue (8-phase 256^2)
    gemm256_qkv_rope<<<dim3(C3 / 256, M / 256), 512, 0, stream>>>(xb, Wab, tab, qkvb, M, C3, CC);

    // 2) transpose V + repack K (contiguous per-head rows)
    vktranspose<<<dim3(BB * NH * (TT / 64)), 256, 0, stream>>>(qkvb, vtb, ktb);

    // 3) MFMA flash attention v8 (zero-barrier, direct-L2 fragments) -> yb (bf16)
    attn_mfma8<<<dim3(BB * NH * 32), 64, 0, stream>>>(qkvb, ktb, vtb, yb);

    // 4) out = yb @ W_proj  (8-phase 256^2, fp32 out)
    gemm256_f32<<<dim3(CC / 256, M / 256), 512, 0, stream>>>(yb, Wpb, out, M, CC, CC);
}

// Round 5
// 281.801 us; speedup vs baseline: 1.1858x; 1.1858x over previous
//
#include <hip/hip_runtime.h>
#include <hip/hip_bf16.h>
#include <math.h>

// Problem constants
#define BB 4
#define TT 2048
#define CC 1024
#define NH 16
#define HD 64
#define C3 3072
#define LDK 72   // padded LDS row stride (bf16 elems) - vtranspose only

// exp2-domain query scale: 0.125 * log2(e)
#define QSCALE 0.18033688011112042f

typedef __attribute__((ext_vector_type(8))) short bf16x8;
typedef __attribute__((ext_vector_type(4))) short bf16x4;
typedef __attribute__((ext_vector_type(4))) float f32x4;

// async global->LDS, 16 B per lane; LDS dest = wave-uniform base + lane*16
__device__ __forceinline__ void gload_lds16(const __hip_bfloat16* g, __hip_bfloat16* s) {
    __builtin_amdgcn_global_load_lds((const __attribute__((address_space(1))) void*)g,
                                     (__attribute__((address_space(3))) void*)s, 16, 0, 0);
}

// ---------------------------------------------------------------------------
// RoPE tables: tab[t*32 + p] = (cos, sin); the only sincosf call site.
// ---------------------------------------------------------------------------
__global__ __launch_bounds__(256) void rope_tables(float2* __restrict__ tab) {
    int idx = blockIdx.x * 256 + threadIdx.x;   // 0..65535
    int t = idx >> 5;
    int p = idx & 31;
    float invf = exp2f((float)p * (-13.287712379549449f / 32.0f));  // 10000^(-p/32)
    float ang = (float)t * invf;
    float s, c;
    sincosf(ang, &s, &c);
    tab[idx] = make_float2(c, s);
}

// ---------------------------------------------------------------------------
// cast fp32 -> bf16, 8 elements/thread
// ---------------------------------------------------------------------------
__global__ __launch_bounds__(256) void cast_bf16x8(const float* __restrict__ X,
                                                   __hip_bfloat16* __restrict__ Y) {
    size_t i = ((size_t)blockIdx.x * 256 + threadIdx.x) * 8;
    float4 a = *(const float4*)(X + i);
    float4 b = *(const float4*)(X + i + 4);
    __align__(16) __hip_bfloat16 tmp[8];
    tmp[0] = __float2bfloat16(a.x);
    tmp[1] = __float2bfloat16(a.y);
    tmp[2] = __float2bfloat16(a.z);
    tmp[3] = __float2bfloat16(a.w);
    tmp[4] = __float2bfloat16(b.x);
    tmp[5] = __float2bfloat16(b.y);
    tmp[6] = __float2bfloat16(b.z);
    tmp[7] = __float2bfloat16(b.w);
    *(bf16x8*)(Y + i) = *(bf16x8*)tmp;
}

// ---------------------------------------------------------------------------
// W[K][N] fp32  ->  Wt[N][K] bf16   (64x64 tiles via LDS)
// ---------------------------------------------------------------------------
__global__ __launch_bounds__(256) void wtrans(const float* __restrict__ W,
                                              __hip_bfloat16* __restrict__ Wt,
                                              int K, int N) {
    __shared__ float st[64][65];
    const int n0 = blockIdx.x * 64;
    const int k0 = blockIdx.y * 64;
    const int tid = threadIdx.x;
    const int r = tid >> 4;
    const int c4 = (tid & 15) * 4;
#pragma unroll
    for (int p = 0; p < 4; ++p) {
        int k = p * 16 + r;
        float4 v = *(const float4*)(W + (size_t)(k0 + k) * N + n0 + c4);
        st[c4 + 0][k] = v.x;
        st[c4 + 1][k] = v.y;
        st[c4 + 2][k] = v.z;
        st[c4 + 3][k] = v.w;
    }
    __syncthreads();
    const int rr = tid >> 3;
    const int cc = (tid & 7) * 8;
#pragma unroll
    for (int p = 0; p < 2; ++p) {
        int n = p * 32 + rr;
        __align__(16) __hip_bfloat16 tmp[8];
#pragma unroll
        for (int j = 0; j < 8; ++j) tmp[j] = __float2bfloat16(st[n][cc + j]);
        *(bf16x8*)(Wt + (size_t)(n0 + n) * K + k0 + cc) = *(bf16x8*)tmp;
    }
}

// ---------------------------------------------------------------------------
// 256x256 8-phase GEMM (T2 st_16x32 swizzle + T3/T4 counted vmcnt + T5 setprio)
// (unchanged — verified in rounds 1-3)
// ---------------------------------------------------------------------------
#define CA0 0
#define CA1 1
#define CB0 2
#define CB1 3

#define BAR() __builtin_amdgcn_s_barrier()
#define SB0() __builtin_amdgcn_sched_barrier(0)
#define WAIT_LGKM0() do { asm volatile("s_waitcnt lgkmcnt(0)" ::: "memory"); SB0(); } while (0)
#define WAIT_VM4()   do { asm volatile("s_waitcnt vmcnt(4)" ::: "memory");  SB0(); } while (0)
#define WAIT_VM0()   do { asm volatile("s_waitcnt vmcnt(0)" ::: "memory");  SB0(); } while (0)

#define CLAMP_TS(x) ((x) < NTILE ? (x) : (x) - 2)

// wave w stages subtile-row w (16 rows) of the chunk: 2 x 1KiB wave-calls
#define STAGE(gbase, h, ts, buf, cid) do {                                            \
    const __hip_bfloat16* _s = (gbase) + (size_t)((h) * 128 + w * 16) * K + (ts) * 64; \
    __hip_bfloat16* _d = &lds[buf][cid][w * 1024];                                    \
    gload_lds16(_s, _d);                                                              \
    gload_lds16(_s + 32, _d + 512);                                                   \
} while (0)

#define FRAGP(buf, cid, rowsub, ks)                                                   \
    ((const bf16x8*)((const char*)&lds[buf][cid][0] +                                 \
        (((rowsub) * 2 + (ks)) << 10) + (l16 << 6) + swzoff))

#define READ_A(buf, mi) do {                                                          \
    _Pragma("unroll") for (int _m = 0; _m < 4; ++_m)                                  \
    _Pragma("unroll") for (int _k = 0; _k < 2; ++_k)                                  \
        af[_m][_k] = *FRAGP(buf, wm, (mi) * 4 + _m, _k);                              \
} while (0)

#define READ_B(buf, ni) do {                                                          \
    _Pragma("unroll") for (int _n = 0; _n < 2; ++_n)                                  \
    _Pragma("unroll") for (int _k = 0; _k < 2; ++_k)                                  \
        bfr[(ni) * 2 + _n][_k] =                                                      \
            *FRAGP(buf, 2 + (wn >> 1), (wn & 1) * 4 + (ni) * 2 + _n, _k);             \
} while (0)

#define MFMA_Q(mb, nb) do {                                                           \
    __builtin_amdgcn_s_setprio(1);                                                    \
    _Pragma("unroll") for (int _m = 0; _m < 4; ++_m)                                  \
    _Pragma("unroll") for (int _n = 0; _n < 2; ++_n)                                  \
    _Pragma("unroll") for (int _k = 0; _k < 2; ++_k)                                  \
        acc[(mb) * 4 + _m][(nb) * 2 + _n] = __builtin_amdgcn_mfma_f32_16x16x32_bf16(  \
            af[_m][_k], bfr[(nb) * 2 + _n][_k], acc[(mb) * 4 + _m][(nb) * 2 + _n],    \
            0, 0, 0);                                                                 \
    __builtin_amdgcn_s_setprio(0);                                                    \
} while (0)

#define HALF_ITER(BUF, T12, B12, T34, B34) do {                                       \
    /* phase A: Q(0,0) */                                                             \
    READ_A(BUF, 0);                                                                   \
    READ_B(BUF, 0);                                                                   \
    STAGE(Bb, 1, CLAMP_TS(T12), B12, CB1);                                            \
    BAR(); WAIT_LGKM0();                                                              \
    MFMA_Q(0, 0);                                                                     \
    BAR();                                                                            \
    /* phase B: Q(0,1) */                                                             \
    READ_B(BUF, 1);                                                                   \
    STAGE(Ab, 1, CLAMP_TS(T12), B12, CA1);                                            \
    BAR(); WAIT_LGKM0();                                                              \
    MFMA_Q(0, 1);                                                                     \
    BAR();                                                                            \
    /* phase C: Q(1,0) */                                                             \
    READ_A(BUF, 1);                                                                   \
    STAGE(Bb, 0, CLAMP_TS(T34), B34, CB0);                                            \
    BAR(); WAIT_LGKM0();                                                              \
    MFMA_Q(1, 0);                                                                     \
    BAR();                                                                            \
    /* phase D: Q(1,1) */                                                             \
    STAGE(Ab, 0, CLAMP_TS(T34), B34, CA0);                                            \
    BAR(); WAIT_LGKM0();                                                              \
    MFMA_Q(1, 1);                                                                     \
    WAIT_VM4();                                                                       \
    BAR(); SB0();                                                                     \
} while (0)

#define GEMM256_BODY                                                                  \
    __shared__ __align__(16) __hip_bfloat16 lds[2][4][8192]; /* 128 KiB */            \
    const int tid = threadIdx.x;                                                      \
    const int w = tid >> 6;                                                           \
    const int lane = tid & 63;                                                        \
    const int l16 = lane & 15;                                                        \
    const int quad = lane >> 4;                                                       \
    const int wm = w >> 2;                                                            \
    const int wn = w & 3;                                                             \
    const int swzoff = ((quad * 8) ^ ((l16 & 8) << 1)) << 1;                          \
    const int bm0 = blockIdx.y * 256;                                                 \
    const int bn0 = blockIdx.x * 256;                                                 \
    const int NTILE = K >> 6;                                                         \
    const size_t laneOff = (size_t)(lane >> 2) * K +                                  \
                           (((lane & 3) * 8) ^ ((lane >> 5) << 4));                   \
    const __hip_bfloat16* Ab = A + (size_t)bm0 * K + laneOff;                         \
    const __hip_bfloat16* Bb = Bt + (size_t)bn0 * K + laneOff;                        \
    f32x4 acc[8][4] = {};                                                             \
    /* prologue: tile0 fully + tile1's CB0/CA0 (matches steady chronology) */         \
    STAGE(Bb, 0, 0, 0, CB0);                                                          \
    STAGE(Ab, 0, 0, 0, CA0);                                                          \
    STAGE(Bb, 1, 0, 0, CB1);                                                          \
    STAGE(Ab, 1, 0, 0, CA1);                                                          \
    STAGE(Bb, 0, 1, 1, CB0);                                                          \
    STAGE(Ab, 0, 1, 1, CA0);                                                          \
    WAIT_VM4();                                                                       \
    BAR(); SB0();                                                                     \
    for (int it = 0; it < NTILE / 2; ++it) {                                          \
        const int t = it * 2;                                                         \
        bf16x8 af[4][2], bfr[4][2];                                                   \
        HALF_ITER(0, t + 1, 1, t + 2, 0);                                             \
        HALF_ITER(1, t + 2, 0, t + 3, 1);                                             \
    }

// ---------------------------------------------------------------------------
// qkv = x @ W_attn with fused interleaved RoPE epilogue (8-phase 256^2 core)
// ---------------------------------------------------------------------------
__global__ __launch_bounds__(512) void gemm256_qkv_rope(const __hip_bfloat16* __restrict__ A,
                                                        const __hip_bfloat16* __restrict__ Bt,
                                                        const float2* __restrict__ tab,
                                                        __hip_bfloat16* __restrict__ C,
                                                        int M, int N, int K) {
    GEMM256_BODY

    if (bn0 < 2048) {
        const float qsc = (bn0 < 1024) ? QSCALE : 1.0f;
        const float sgn = (l16 & 1) ? 1.0f : -1.0f;
#pragma unroll
        for (int mt = 0; mt < 8; ++mt) {
            int row = bm0 + wm * 128 + mt * 16 + quad * 4;
#pragma unroll
            for (int nt = 0; nt < 4; ++nt) {
                int col = bn0 + wn * 64 + nt * 16 + l16;
                int p2 = nt * 8 + (l16 >> 1);
#pragma unroll
                for (int r = 0; r < 4; ++r) {
                    float own = acc[mt][nt][r];
                    float part = __shfl_xor(own, 1);
                    int trow = (row + r) & (TT - 1);
                    float2 cs = tab[(trow << 5) + p2];
                    float res = (own * cs.x + sgn * part * cs.y) * qsc;
                    C[(size_t)(row + r) * N + col] = __float2bfloat16(res);
                }
            }
        }
    } else {
#pragma unroll
        for (int mt = 0; mt < 8; ++mt) {
            int row = bm0 + wm * 128 + mt * 16 + quad * 4;
#pragma unroll
            for (int nt = 0; nt < 4; ++nt) {
                int col = bn0 + wn * 64 + nt * 16 + l16;
#pragma unroll
                for (int r = 0; r < 4; ++r)
                    C[(size_t)(row + r) * N + col] = __float2bfloat16(acc[mt][nt][r]);
            }
        }
    }
}

// ---------------------------------------------------------------------------
// out-proj GEMM, fp32 store (8-phase 256^2 core)
// ---------------------------------------------------------------------------
__global__ __launch_bounds__(512) void gemm256_f32(const __hip_bfloat16* __restrict__ A,
                                                   const __hip_bfloat16* __restrict__ Bt,
                                                   float* __restrict__ C,
                                                   int M, int N, int K) {
    GEMM256_BODY
#pragma unroll
    for (int mt = 0; mt < 8; ++mt) {
        int row = bm0 + wm * 128 + mt * 16 + quad * 4;
#pragma unroll
        for (int nt = 0; nt < 4; ++nt) {
            int col = bn0 + wn * 64 + nt * 16 + l16;
#pragma unroll
            for (int r = 0; r < 4; ++r)
                C[(size_t)(row + r) * N + col] = acc[mt][nt][r];
        }
    }
}

// ---------------------------------------------------------------------------
// Transpose V with PV-fragment key permutation:
//   vtb position (within each 64-key tile) p holds key c', where
//     p(c') = (c'&32) | ((c'>>2)&3)<<3 | ((c'>>4)&1)<<2 | (c'&3)   (bijective)
// This makes the PV A-operand (P fragments) LANE-LOCAL in the attn kernel:
// after S^T=K*Q^T, lane quad q' holds exactly the St values that slot into
// A-operand k-octet q' under this V column order -> no LDS P round-trip.
// (Contraction sum is permutation-invariant; masking uses actual keys.)
// ---------------------------------------------------------------------------
__global__ __launch_bounds__(256) void vtranspose(const __hip_bfloat16* __restrict__ qkvb,
                                                  __hip_bfloat16* __restrict__ vtb) {
    __shared__ __align__(16) __hip_bfloat16 st[64][LDK];
    const int bh = blockIdx.x >> 5;
    const int tt = blockIdx.x & 31;
    const int b = bh >> 4;
    const int h = bh & 15;
    const int tid = threadIdx.x;
    const int row = tid >> 3;
    const int a = tid & 7;
    const int col8 = a * 8;

#pragma unroll
    for (int pass = 0; pass < 2; ++pass) {
        int t = pass * 32 + row;
        *(bf16x8*)(&st[t][col8]) =
            *(const bf16x8*)(qkvb + ((size_t)(b * TT + tt * 64 + t)) * C3 + 2 * CC + h * HD + col8);
    }
    __syncthreads();
    // permuted write positions: keys c' = 8a+j ->
    //   j=0..3: p0 + j,  j=4..7: p1 + (j-4)
    const int h32 = (a >> 2) & 1;
    const int m4  = (a >> 1) & 1;
    const int p0 = h32 * 32 + ((2 * a) & 3) * 8 + m4 * 4;
    const int p1 = h32 * 32 + ((2 * a + 1) & 3) * 8 + m4 * 4;
#pragma unroll
    for (int pass = 0; pass < 2; ++pass) {
        int d = pass * 32 + row;
        __align__(16) __hip_bfloat16 tmp[8];
#pragma unroll
        for (int j = 0; j < 8; ++j) tmp[j] = st[col8 + j][d];
        __hip_bfloat16* dst = vtb + ((size_t)bh * HD + d) * TT + tt * 64;
        *(bf16x4*)(dst + p0) = *(const bf16x4*)&tmp[0];
        *(bf16x4*)(dst + p1) = *(const bf16x4*)&tmp[4];
    }
}

// ---------------------------------------------------------------------------
// MFMA flash attention v9 (causal): v6's verified skeleton (S^T form,
// fixed-max exp2 softmax, uniform paired query-blocks, 3-deep counted-vmcnt
// K/V pipeline) with TWO deltas:
//   1. P stays in registers: V key-columns are pre-permuted (vtranspose) so
//      the PV A-operand is lane-local -> the per-qtile Ps LDS round-trip
//      (4 ds_write + lgkmcnt(0) drain + 2 ds_read + bank conflicts) is GONE.
//   2. XCD-chunked blockIdx remap: each bh's 8 blocks share one XCD's L2
//      (K+V per bh = 512 KB; 8 bh x 512 KB = 4 MB = one L2).
// ---------------------------------------------------------------------------
__global__ __launch_bounds__(256) void attn_mfma9(const __hip_bfloat16* __restrict__ qkvb,
                                                  const __hip_bfloat16* __restrict__ vtb,
                                                  __hip_bfloat16* __restrict__ y) {
    __shared__ __align__(16) __hip_bfloat16 Kb[3][64 * 64];   // [key][dim], XOR-swizzled
    __shared__ __align__(16) __hip_bfloat16 Vb[3][64 * 64];   // [dim][key], XOR-swizzled

    const int tid = threadIdx.x;
    const int w = tid >> 6;
    const int lane = tid & 63;
    const int l16 = lane & 15;
    const int quad = lane >> 4;
    const int swz = l16 & 7;

    const int rb = blockIdx.x;
    const int lb = (rb & 7) * 64 + (rb >> 3);   // XCD-chunked bijective remap (512 = 8*64)
    const int bh = lb >> 3;
    const int pr = lb & 7;
    const int b = bh >> 4;
    const int h = bh & 15;

    const int sr = (lane >> 3) & 7;
    const int sc = lane & 7;
    const int klog = (sc ^ sr) * 8;

    const __hip_bfloat16* kbase = qkvb + (size_t)b * TT * C3 + CC + h * HD + klog;
    const __hip_bfloat16* vbase = vtb + (size_t)bh * HD * TT + klog;

#define ATTN_STAGE(t, bidx) do {                                                  \
    _Pragma("unroll")                                                             \
    for (int half = 0; half < 2; ++half) {                                        \
        int kr = w * 16 + half * 8 + sr;                                          \
        gload_lds16(kbase + (size_t)((t) * 64 + kr) * C3,                         \
                    Kb[bidx] + (w * 16 + half * 8) * 64);                         \
        gload_lds16(vbase + (size_t)kr * TT + (t) * 64,                           \
                    Vb[bidx] + (w * 16 + half * 8) * 64);                         \
    }                                                                             \
} while (0)

#pragma unroll
    for (int seg = 0; seg < 2; ++seg) {
        const int qblk = (seg == 0) ? (15 - pr) : pr;
        const int qb = qblk * 128;
        const int jtmax = 2 * qblk + 1;
        const int qn0 = qb + w * 32;
        const int qn1 = qn0 + 16;

        // Q B-frags (B[k=dim][n=query]), rope'd + exp2-scaled already
        bf16x8 qf[2][2];
#pragma unroll
        for (int qt = 0; qt < 2; ++qt) {
            const __hip_bfloat16* qp = qkvb + (size_t)(b * TT + qn0 + qt * 16 + l16) * C3 + h * HD;
            qf[qt][0] = *(const bf16x8*)(qp + quad * 8);
            qf[qt][1] = *(const bf16x8*)(qp + 32 + quad * 8);
        }

        f32x4 O[2][4] = {};
        float l_q[2] = {0.f, 0.f};                // per-quad partial; reduced in epilogue

        __syncthreads();   // full drain: buffers from previous segment consumed
        // prologue: stage tiles 0 and 1 into buffers 0 and 1 (4 vm-events each/wave)
        ATTN_STAGE(0, 0);
        ATTN_STAGE(1, 1);

        int bcur = 0;      // LDS buffer holding tile jt
        for (int jt = 0; jt <= jtmax; ++jt) {
            // own 4 loads of tile jt complete; tile jt+1's 4 may stay in flight
            if (jt < jtmax) { WAIT_VM4(); } else { WAIT_VM0(); }
            BAR(); SB0();   // raw barrier, no counter drain

            if (jt + 2 <= jtmax) {
                const int bs = (bcur >= 1) ? (bcur - 1) : 2;   // (bcur+2)%3
                ATTN_STAGE(jt + 2, bs);
            }

            const __hip_bfloat16* Kp = Kb[bcur];
            const __hip_bfloat16* Vp = Vb[bcur];

            const bool sk0 = (jt * 64 > qn0 + 15);
            const bool sk1 = (jt * 64 > qn1 + 15);

            if (!sk1) {
                // ---- S^T = K * Q^T (exp2 domain, zero-init) ----
                f32x4 St[2][4] = {};
                __builtin_amdgcn_s_setprio(1);
#pragma unroll
                for (int ks = 0; ks < 2; ++ks) {
#pragma unroll
                    for (int mt = 0; mt < 4; ++mt) {
                        bf16x8 kf = *(const bf16x8*)(Kp + (mt * 16 + l16) * 64 +
                                                     ((ks * 4 + quad) ^ swz) * 8);
                        St[0][mt] = __builtin_amdgcn_mfma_f32_16x16x32_bf16(kf, qf[0][ks], St[0][mt], 0, 0, 0);
                        St[1][mt] = __builtin_amdgcn_mfma_f32_16x16x32_bf16(kf, qf[1][ks], St[1][mt], 0, 0, 0);
                    }
                }
                __builtin_amdgcn_s_setprio(0);

                // ---- V-frags (shared by both qtiles); permuted key order ----
                bf16x8 vf[4][2];
#pragma unroll
                for (int dt = 0; dt < 4; ++dt) {
                    vf[dt][0] = *(const bf16x8*)(Vp + (dt * 16 + l16) * 64 + ((quad) ^ swz) * 8);
                    vf[dt][1] = *(const bf16x8*)(Vp + (dt * 16 + l16) * 64 + ((4 + quad) ^ swz) * 8);
                }

                // ---- per-qtile: mask, exp2, REGISTER pack, PV (no LDS) ----
#pragma unroll
                for (int qt = 0; qt < 2; ++qt) {
                    const bool skq = qt == 0 ? sk0 : sk1;
                    if (skq) continue;
                    const int qn = qt == 0 ? qn0 : qn1;
                    if (jt * 64 + 63 > qn) {        // diagonal tile: causal mask
#pragma unroll
                        for (int mt = 0; mt < 4; ++mt) {
#pragma unroll
                            for (int r = 0; r < 4; ++r) {
                                int key = jt * 64 + mt * 16 + quad * 4 + r;
                                if (key > qn + l16) St[qt][mt][r] = -__builtin_inff();
                            }
                        }
                    }
                    float sum = 0.f;
                    union { bf16x8 v; __hip_bfloat162 hh[4]; } pk0, pk1;
#pragma unroll
                    for (int mt = 0; mt < 4; ++mt) {
                        float e0 = exp2f(St[qt][mt][0]);
                        float e1 = exp2f(St[qt][mt][1]);
                        float e2 = exp2f(St[qt][mt][2]);
                        float e3 = exp2f(St[qt][mt][3]);
                        sum += (e0 + e1) + (e2 + e3);
                        __hip_bfloat162 lo = __float22bfloat162_rn(make_float2(e0, e1));
                        __hip_bfloat162 hi = __float22bfloat162_rn(make_float2(e2, e3));
                        if (mt < 2) { pk0.hh[mt * 2] = lo; pk0.hh[mt * 2 + 1] = hi; }
                        else        { pk1.hh[(mt - 2) * 2] = lo; pk1.hh[(mt - 2) * 2 + 1] = hi; }
                    }
                    l_q[qt] += sum;

                    __builtin_amdgcn_s_setprio(1);
#pragma unroll
                    for (int dt = 0; dt < 4; ++dt) {
                        O[qt][dt] = __builtin_amdgcn_mfma_f32_16x16x32_bf16(pk0.v, vf[dt][0], O[qt][dt], 0, 0, 0);
                        O[qt][dt] = __builtin_amdgcn_mfma_f32_16x16x32_bf16(pk1.v, vf[dt][1], O[qt][dt], 0, 0, 0);
                    }
                    __builtin_amdgcn_s_setprio(0);
                }
            }

            bcur = (bcur == 2) ? 0 : bcur + 1;
        }

        // ---- epilogue: reduce l across quads, normalize, store ----
#pragma unroll
        for (int qt = 0; qt < 2; ++qt) {
            float l2 = l_q[qt];
            l2 += __shfl_xor(l2, 16);
            l2 += __shfl_xor(l2, 32);
            float lO[4];
#pragma unroll
            for (int r = 0; r < 4; ++r) lO[r] = 1.0f / __shfl(l2, quad * 4 + r);
            const int qbase = qn0 + qt * 16 + quad * 4;
#pragma unroll
            for (int dt = 0; dt < 4; ++dt) {
#pragma unroll
                for (int r = 0; r < 4; ++r) {
                    y[(size_t)(b * TT + qbase + r) * CC + h * HD + dt * 16 + l16] =
                        __float2bfloat16(O[qt][dt][r] * lO[r]);
                }
            }
        }
    }
#undef ATTN_STAGE
}

// ---------------------------------------------------------------------------
extern "C" void kernel_launch(void* const* d_in, const int* in_sizes, int n_in,
                              void* d_out, int out_size, void* d_ws, size_t ws_size,
                              hipStream_t stream) {
    const float* x      = (const float*)d_in[0];   // (B,T,C)
    const float* W_attn = (const float*)d_in[1];   // (C, 3C)
    const float* W_proj = (const float*)d_in[2];   // (C, C)
    float* out = (float*)d_out;                    // (B,T,C)

    const size_t NBT = (size_t)BB * TT;            // 8192
    __hip_bfloat16* xb   = (__hip_bfloat16*)d_ws;           // B*T*C (reused as yb)
    __hip_bfloat16* qkvb = xb + NBT * CC;                   // B*T*3C
    __hip_bfloat16* vtb  = qkvb + NBT * C3;                 // B*H*64*T
    __hip_bfloat16* Wab  = vtb + NBT * CC;                  // 3C*C  [N][K]
    __hip_bfloat16* Wpb  = Wab + (size_t)CC * C3;           // C*C   [N][K]
    float2* tab          = (float2*)(Wpb + (size_t)CC * CC); // T*32 float2 = 512 KB
    __hip_bfloat16* yb   = xb;                              // reuse after qkv GEMM

    const int M = BB * TT;   // 8192

    rope_tables<<<dim3(TT * 32 / 256), 256, 0, stream>>>(tab);
    cast_bf16x8<<<dim3((int)(NBT * CC / 2048)), 256, 0, stream>>>(x, xb);
    wtrans<<<dim3(C3 / 64, CC / 64), 256, 0, stream>>>(W_attn, Wab, CC, C3);
    wtrans<<<dim3(CC / 64, CC / 64), 256, 0, stream>>>(W_proj, Wpb, CC, CC);

    // 1) qkv = x @ W_attn with fused table-RoPE epilogue (8-phase 256^2)
    gemm256_qkv_rope<<<dim3(C3 / 256, M / 256), 512, 0, stream>>>(xb, Wab, tab, qkvb, M, C3, CC);

    // 2) transpose V (with PV-fragment key permutation)
    vtranspose<<<dim3(BB * NH * (TT / 64)), 256, 0, stream>>>(qkvb, vtb);

    // 3) MFMA flash attention v9 (register-P + XCD remap) -> yb (bf16)
    attn_mfma9<<<dim3(BB * NH * 8), 256, 0, stream>>>(qkvb, vtb, yb);

    // 4) out = yb @ W_proj  (8-phase 256^2, fp32 out)
    gemm256_f32<<<dim3(CC / 256, M / 256), 512, 0, stream>>>(yb, Wpb, out, M, CC, CC);
}

// Round 6
// 271.913 us; speedup vs baseline: 1.2289x; 1.0364x over previous
//
#include <hip/hip_runtime.h>
#include <hip/hip_bf16.h>
#include <math.h>

// Problem constants
#define BB 4
#define TT 2048
#define CC 1024
#define NH 16
#define HD 64
#define C3 3072
#define LDK 72   // padded LDS row stride (bf16 elems) - vtranspose only

// exp2-domain query scale: 0.125 * log2(e)
#define QSCALE 0.18033688011112042f

typedef __attribute__((ext_vector_type(8))) short bf16x8;
typedef __attribute__((ext_vector_type(4))) short bf16x4;
typedef __attribute__((ext_vector_type(4))) float f32x4;

// async global->LDS, 16 B per lane; LDS dest = wave-uniform base + lane*16
__device__ __forceinline__ void gload_lds16(const __hip_bfloat16* g, __hip_bfloat16* s) {
    __builtin_amdgcn_global_load_lds((const __attribute__((address_space(1))) void*)g,
                                     (__attribute__((address_space(3))) void*)s, 16, 0, 0);
}

// ---------------------------------------------------------------------------
// RoPE tables: tab[t*32 + p] = (cos, sin); the only sincosf call site.
// ---------------------------------------------------------------------------
__global__ __launch_bounds__(256) void rope_tables(float2* __restrict__ tab) {
    int idx = blockIdx.x * 256 + threadIdx.x;   // 0..65535
    int t = idx >> 5;
    int p = idx & 31;
    float invf = exp2f((float)p * (-13.287712379549449f / 32.0f));  // 10000^(-p/32)
    float ang = (float)t * invf;
    float s, c;
    sincosf(ang, &s, &c);
    tab[idx] = make_float2(c, s);
}

// ---------------------------------------------------------------------------
// cast fp32 -> bf16, 8 elements/thread
// ---------------------------------------------------------------------------
__global__ __launch_bounds__(256) void cast_bf16x8(const float* __restrict__ X,
                                                   __hip_bfloat16* __restrict__ Y) {
    size_t i = ((size_t)blockIdx.x * 256 + threadIdx.x) * 8;
    float4 a = *(const float4*)(X + i);
    float4 b = *(const float4*)(X + i + 4);
    __align__(16) __hip_bfloat16 tmp[8];
    tmp[0] = __float2bfloat16(a.x);
    tmp[1] = __float2bfloat16(a.y);
    tmp[2] = __float2bfloat16(a.z);
    tmp[3] = __float2bfloat16(a.w);
    tmp[4] = __float2bfloat16(b.x);
    tmp[5] = __float2bfloat16(b.y);
    tmp[6] = __float2bfloat16(b.z);
    tmp[7] = __float2bfloat16(b.w);
    *(bf16x8*)(Y + i) = *(bf16x8*)tmp;
}

// ---------------------------------------------------------------------------
// W[K][N] fp32  ->  Wt[N][K] bf16   (64x64 tiles via LDS)
// ---------------------------------------------------------------------------
__global__ __launch_bounds__(256) void wtrans(const float* __restrict__ W,
                                              __hip_bfloat16* __restrict__ Wt,
                                              int K, int N) {
    __shared__ float st[64][65];
    const int n0 = blockIdx.x * 64;
    const int k0 = blockIdx.y * 64;
    const int tid = threadIdx.x;
    const int r = tid >> 4;
    const int c4 = (tid & 15) * 4;
#pragma unroll
    for (int p = 0; p < 4; ++p) {
        int k = p * 16 + r;
        float4 v = *(const float4*)(W + (size_t)(k0 + k) * N + n0 + c4);
        st[c4 + 0][k] = v.x;
        st[c4 + 1][k] = v.y;
        st[c4 + 2][k] = v.z;
        st[c4 + 3][k] = v.w;
    }
    __syncthreads();
    const int rr = tid >> 3;
    const int cc = (tid & 7) * 8;
#pragma unroll
    for (int p = 0; p < 2; ++p) {
        int n = p * 32 + rr;
        __align__(16) __hip_bfloat16 tmp[8];
#pragma unroll
        for (int j = 0; j < 8; ++j) tmp[j] = __float2bfloat16(st[n][cc + j]);
        *(bf16x8*)(Wt + (size_t)(n0 + n) * K + k0 + cc) = *(bf16x8*)tmp;
    }
}

// ---------------------------------------------------------------------------
// 256x256 8-phase GEMM core (T2 swizzle + T3/T4 counted vmcnt + T5 setprio).
// bm0/bn0 must be defined by the caller (enables XCD-chunked remap).
// ---------------------------------------------------------------------------
#define CA0 0
#define CA1 1
#define CB0 2
#define CB1 3

#define BAR() __builtin_amdgcn_s_barrier()
#define SB0() __builtin_amdgcn_sched_barrier(0)
#define WAIT_LGKM0() do { asm volatile("s_waitcnt lgkmcnt(0)" ::: "memory"); SB0(); } while (0)
#define WAIT_VM4()   do { asm volatile("s_waitcnt vmcnt(4)" ::: "memory");  SB0(); } while (0)
#define WAIT_VM3()   do { asm volatile("s_waitcnt vmcnt(3)" ::: "memory");  SB0(); } while (0)
#define WAIT_VM0()   do { asm volatile("s_waitcnt vmcnt(0)" ::: "memory");  SB0(); } while (0)

#define CLAMP_TS(x) ((x) < NTILE ? (x) : (x) - 2)

// wave w stages subtile-row w (16 rows) of the chunk: 2 x 1KiB wave-calls
#define STAGE(gbase, h, ts, buf, cid) do {                                            \
    const __hip_bfloat16* _s = (gbase) + (size_t)((h) * 128 + w * 16) * K + (ts) * 64; \
    __hip_bfloat16* _d = &lds[buf][cid][w * 1024];                                    \
    gload_lds16(_s, _d);                                                              \
    gload_lds16(_s + 32, _d + 512);                                                   \
} while (0)

#define FRAGP(buf, cid, rowsub, ks)                                                   \
    ((const bf16x8*)((const char*)&lds[buf][cid][0] +                                 \
        (((rowsub) * 2 + (ks)) << 10) + (l16 << 6) + swzoff))

#define READ_A(buf, mi) do {                                                          \
    _Pragma("unroll") for (int _m = 0; _m < 4; ++_m)                                  \
    _Pragma("unroll") for (int _k = 0; _k < 2; ++_k)                                  \
        af[_m][_k] = *FRAGP(buf, wm, (mi) * 4 + _m, _k);                              \
} while (0)

#define READ_B(buf, ni) do {                                                          \
    _Pragma("unroll") for (int _n = 0; _n < 2; ++_n)                                  \
    _Pragma("unroll") for (int _k = 0; _k < 2; ++_k)                                  \
        bfr[(ni) * 2 + _n][_k] =                                                      \
            *FRAGP(buf, 2 + (wn >> 1), (wn & 1) * 4 + (ni) * 2 + _n, _k);             \
} while (0)

#define MFMA_Q(mb, nb) do {                                                           \
    __builtin_amdgcn_s_setprio(1);                                                    \
    _Pragma("unroll") for (int _m = 0; _m < 4; ++_m)                                  \
    _Pragma("unroll") for (int _n = 0; _n < 2; ++_n)                                  \
    _Pragma("unroll") for (int _k = 0; _k < 2; ++_k)                                  \
        acc[(mb) * 4 + _m][(nb) * 2 + _n] = __builtin_amdgcn_mfma_f32_16x16x32_bf16(  \
            af[_m][_k], bfr[(nb) * 2 + _n][_k], acc[(mb) * 4 + _m][(nb) * 2 + _n],    \
            0, 0, 0);                                                                 \
    __builtin_amdgcn_s_setprio(0);                                                    \
} while (0)

#define HALF_ITER(BUF, T12, B12, T34, B34) do {                                       \
    /* phase A: Q(0,0) */                                                             \
    READ_A(BUF, 0);                                                                   \
    READ_B(BUF, 0);                                                                   \
    STAGE(Bb, 1, CLAMP_TS(T12), B12, CB1);                                            \
    BAR(); WAIT_LGKM0();                                                              \
    MFMA_Q(0, 0);                                                                     \
    BAR();                                                                            \
    /* phase B: Q(0,1) */                                                             \
    READ_B(BUF, 1);                                                                   \
    STAGE(Ab, 1, CLAMP_TS(T12), B12, CA1);                                            \
    BAR(); WAIT_LGKM0();                                                              \
    MFMA_Q(0, 1);                                                                     \
    BAR();                                                                            \
    /* phase C: Q(1,0) */                                                             \
    READ_A(BUF, 1);                                                                   \
    STAGE(Bb, 0, CLAMP_TS(T34), B34, CB0);                                            \
    BAR(); WAIT_LGKM0();                                                              \
    MFMA_Q(1, 0);                                                                     \
    BAR();                                                                            \
    /* phase D: Q(1,1) */                                                             \
    STAGE(Ab, 0, CLAMP_TS(T34), B34, CA0);                                            \
    BAR(); WAIT_LGKM0();                                                              \
    MFMA_Q(1, 1);                                                                     \
    WAIT_VM4();                                                                       \
    BAR(); SB0();                                                                     \
} while (0)

#define GEMM256_BODY                                                                  \
    __shared__ __align__(16) __hip_bfloat16 lds[2][4][8192]; /* 128 KiB */            \
    const int tid = threadIdx.x;                                                      \
    const int w = tid >> 6;                                                           \
    const int lane = tid & 63;                                                        \
    const int l16 = lane & 15;                                                        \
    const int quad = lane >> 4;                                                       \
    const int wm = w >> 2;                                                            \
    const int wn = w & 3;                                                             \
    const int swzoff = ((quad * 8) ^ ((l16 & 8) << 1)) << 1;                          \
    const int NTILE = K >> 6;                                                         \
    const size_t laneOff = (size_t)(lane >> 2) * K +                                  \
                           (((lane & 3) * 8) ^ ((lane >> 5) << 4));                   \
    const __hip_bfloat16* Ab = A + (size_t)bm0 * K + laneOff;                         \
    const __hip_bfloat16* Bb = Bt + (size_t)bn0 * K + laneOff;                        \
    f32x4 acc[8][4] = {};                                                             \
    /* prologue: tile0 fully + tile1's CB0/CA0 (matches steady chronology) */         \
    STAGE(Bb, 0, 0, 0, CB0);                                                          \
    STAGE(Ab, 0, 0, 0, CA0);                                                          \
    STAGE(Bb, 1, 0, 0, CB1);                                                          \
    STAGE(Ab, 1, 0, 0, CA1);                                                          \
    STAGE(Bb, 0, 1, 1, CB0);                                                          \
    STAGE(Ab, 0, 1, 1, CA0);                                                          \
    WAIT_VM4();                                                                       \
    BAR(); SB0();                                                                     \
    for (int it = 0; it < NTILE / 2; ++it) {                                          \
        const int t = it * 2;                                                         \
        bf16x8 af[4][2], bfr[4][2];                                                   \
        HALF_ITER(0, t + 1, 1, t + 2, 0);                                             \
        HALF_ITER(1, t + 2, 0, t + 3, 1);                                             \
    }

// ---------------------------------------------------------------------------
// qkv = x @ W_attn with fused interleaved RoPE epilogue (8-phase 256^2 core)
// 1-D grid of 384 blocks, XCD-chunked remap (q = 48): each XCD owns 4
// contiguous A-row-panels -> A staging becomes XCD-private L2 hits.
// ---------------------------------------------------------------------------
__global__ __launch_bounds__(512) void gemm256_qkv_rope(const __hip_bfloat16* __restrict__ A,
                                                        const __hip_bfloat16* __restrict__ Bt,
                                                        const float2* __restrict__ tab,
                                                        __hip_bfloat16* __restrict__ C,
                                                        int M, int N, int K) {
    const int lin = blockIdx.x;                  // 0..383
    const int nl = (lin & 7) * 48 + (lin >> 3);  // bijective (384 = 8*48)
    const int bn0 = (nl % 12) * 256;
    const int bm0 = (nl / 12) * 256;
    GEMM256_BODY

    if (bn0 < 2048) {
        const float qsc = (bn0 < 1024) ? QSCALE : 1.0f;
        const float sgn = (l16 & 1) ? 1.0f : -1.0f;
#pragma unroll
        for (int mt = 0; mt < 8; ++mt) {
            int row = bm0 + wm * 128 + mt * 16 + quad * 4;
#pragma unroll
            for (int nt = 0; nt < 4; ++nt) {
                int col = bn0 + wn * 64 + nt * 16 + l16;
                int p2 = nt * 8 + (l16 >> 1);
#pragma unroll
                for (int r = 0; r < 4; ++r) {
                    float own = acc[mt][nt][r];
                    float part = __shfl_xor(own, 1);
                    int trow = (row + r) & (TT - 1);
                    float2 cs = tab[(trow << 5) + p2];
                    float res = (own * cs.x + sgn * part * cs.y) * qsc;
                    C[(size_t)(row + r) * N + col] = __float2bfloat16(res);
                }
            }
        }
    } else {
#pragma unroll
        for (int mt = 0; mt < 8; ++mt) {
            int row = bm0 + wm * 128 + mt * 16 + quad * 4;
#pragma unroll
            for (int nt = 0; nt < 4; ++nt) {
                int col = bn0 + wn * 64 + nt * 16 + l16;
#pragma unroll
                for (int r = 0; r < 4; ++r)
                    C[(size_t)(row + r) * N + col] = __float2bfloat16(acc[mt][nt][r]);
            }
        }
    }
}

// ---------------------------------------------------------------------------
// out-proj GEMM: 128x256 tile, 8-phase schedule, fp32 store.
// Grid = (1024/256)*(8192/128) = 256 blocks -> ONE full scheduling round
// (vs 128 blocks / half-idle machine with the 256^2 tile).
// Chunks: CA0/CA1 = 64 A-rows (8 KB, ONE gload event each); CB0/CB1 = 128
// B-rows (16 KB, two events). 6 events per half-iter -> counted vmcnt(3)
// retires exactly the 6 chunk-events of the tile entered next. LDS 96 KiB.
// Liveness identical to the 256^2 body: B-chunks dead after phase B,
// A-chunks after phase C; every stage writes a dead (or identical-data
// tail) region.
// ---------------------------------------------------------------------------
__global__ __launch_bounds__(512) void gemm128_f32(const __hip_bfloat16* __restrict__ A,
                                                   const __hip_bfloat16* __restrict__ Bt,
                                                   float* __restrict__ C,
                                                   int M, int N, int K) {
    __shared__ __align__(16) __hip_bfloat16 lds[2][24576];  // CA0@0, CA1@4096, CB0@8192, CB1@16384 (elems)
    const int tid = threadIdx.x;
    const int w = tid >> 6;
    const int lane = tid & 63;
    const int l16 = lane & 15;
    const int quad = lane >> 4;
    const int wm = w >> 2;          // 0..1 -> M rows [wm*64, +64)
    const int wn = w & 3;           // 0..3 -> N cols [wn*64, +64)
    const int swzoff = ((quad * 8) ^ ((l16 & 8) << 1)) << 1;
    const int lin = blockIdx.x;                  // 0..255
    const int nl = (lin & 7) * 32 + (lin >> 3);  // bijective (256 = 8*32)
    const int bn0 = (nl & 3) * 256;
    const int bm0 = (nl >> 2) * 128;
    const int NTILE = K >> 6;
    const int aswz = ((lane & 3) * 8) ^ ((lane >> 5) << 4);
    const size_t laneOff = (size_t)(lane >> 2) * K + aswz;
    const __hip_bfloat16* Ab = A + (size_t)bm0 * K;          // per-call rows
    const __hip_bfloat16* Bb = Bt + (size_t)bn0 * K + laneOff;
    f32x4 acc[4][4] = {};

// A-chunk h (64 rows): one 1-KiB wave-call; wave w covers subtile (w&3, ks=w>>2)
#define STAGE_A128(h, ts, buf) do {                                                   \
    const __hip_bfloat16* _s = Ab + (size_t)((h) * 64 + (w & 3) * 16 + (lane >> 2)) * K \
                               + (ts) * 64 + (w >> 2) * 32 + aswz;                    \
    gload_lds16(_s, &lds[buf][(h) * 4096 + ((w & 3) * 2 + (w >> 2)) * 512]);          \
} while (0)

// B-chunk h (128 rows): two 1-KiB wave-calls (identical to the 256^2 B path)
#define STAGE_B128(h, ts, buf) do {                                                   \
    const __hip_bfloat16* _s = Bb + (size_t)((h) * 128 + w * 16) * K + (ts) * 64;     \
    __hip_bfloat16* _d = &lds[buf][8192 + (h) * 8192 + w * 1024];                     \
    gload_lds16(_s, _d);                                                              \
    gload_lds16(_s + 32, _d + 512);                                                   \
} while (0)

#define FRAGA128(buf, m_, ks)                                                         \
    ((const bf16x8*)((const char*)&lds[buf][wm * 4096] +                              \
        ((((m_) * 2 + (ks)) << 10) + (l16 << 6) + swzoff)))
#define FRAGB128(buf, n_, ks)                                                         \
    ((const bf16x8*)((const char*)&lds[buf][8192 + (wn >> 1) * 8192] +                \
        (((((wn & 1) * 4 + (n_)) * 2 + (ks)) << 10) + (l16 << 6) + swzoff)))

#define READA128(buf, mi) do {                                                        \
    _Pragma("unroll") for (int _m = 0; _m < 2; ++_m)                                  \
    _Pragma("unroll") for (int _k = 0; _k < 2; ++_k)                                  \
        af[(mi) * 2 + _m][_k] = *FRAGA128(buf, (mi) * 2 + _m, _k);                    \
} while (0)

#define READB128(buf, ni) do {                                                        \
    _Pragma("unroll") for (int _n = 0; _n < 2; ++_n)                                  \
    _Pragma("unroll") for (int _k = 0; _k < 2; ++_k)                                  \
        bfr[(ni) * 2 + _n][_k] = *FRAGB128(buf, (ni) * 2 + _n, _k);                   \
} while (0)

#define MFMA8(mb, nb) do {                                                            \
    __builtin_amdgcn_s_setprio(1);                                                    \
    _Pragma("unroll") for (int _m = 0; _m < 2; ++_m)                                  \
    _Pragma("unroll") for (int _n = 0; _n < 2; ++_n)                                  \
    _Pragma("unroll") for (int _k = 0; _k < 2; ++_k)                                  \
        acc[(mb) * 2 + _m][(nb) * 2 + _n] = __builtin_amdgcn_mfma_f32_16x16x32_bf16(  \
            af[(mb) * 2 + _m][_k], bfr[(nb) * 2 + _n][_k],                            \
            acc[(mb) * 2 + _m][(nb) * 2 + _n], 0, 0, 0);                              \
    __builtin_amdgcn_s_setprio(0);                                                    \
} while (0)

#define HALF128(BUF, T12, B12, T34, B34) do {                                         \
    READA128(BUF, 0);                                                                 \
    READB128(BUF, 0);                                                                 \
    STAGE_B128(1, CLAMP_TS(T12), B12);                                                \
    BAR(); WAIT_LGKM0();                                                              \
    MFMA8(0, 0);                                                                      \
    BAR();                                                                            \
    READB128(BUF, 1);                                                                 \
    STAGE_A128(1, CLAMP_TS(T12), B12);                                                \
    BAR(); WAIT_LGKM0();                                                              \
    MFMA8(0, 1);                                                                      \
    BAR();                                                                            \
    READA128(BUF, 1);                                                                 \
    STAGE_B128(0, CLAMP_TS(T34), B34);                                                \
    BAR(); WAIT_LGKM0();                                                              \
    MFMA8(1, 0);                                                                      \
    BAR();                                                                            \
    STAGE_A128(0, CLAMP_TS(T34), B34);                                                \
    BAR(); WAIT_LGKM0();                                                              \
    MFMA8(1, 1);                                                                      \
    WAIT_VM3();                                                                       \
    BAR(); SB0();                                                                     \
} while (0)

    // prologue: tile0 fully + tile1's CB0/CA0 (9 events; wait(3) retires tile0's 6)
    STAGE_B128(0, 0, 0);
    STAGE_A128(0, 0, 0);
    STAGE_B128(1, 0, 0);
    STAGE_A128(1, 0, 0);
    STAGE_B128(0, 1, 1);
    STAGE_A128(0, 1, 1);
    WAIT_VM3();
    BAR(); SB0();
    for (int it = 0; it < NTILE / 2; ++it) {
        const int t = it * 2;
        bf16x8 af[4][2], bfr[4][2];
        HALF128(0, t + 1, 1, t + 2, 0);
        HALF128(1, t + 2, 0, t + 3, 1);
    }
    WAIT_VM0();   // drain tail re-stages before epilogue/endpgm

#pragma unroll
    for (int mt = 0; mt < 4; ++mt) {
        int row = bm0 + wm * 64 + mt * 16 + quad * 4;
#pragma unroll
        for (int nt = 0; nt < 4; ++nt) {
            int col = bn0 + wn * 64 + nt * 16 + l16;
#pragma unroll
            for (int r = 0; r < 4; ++r)
                C[(size_t)(row + r) * N + col] = acc[mt][nt][r];
        }
    }
#undef STAGE_A128
#undef STAGE_B128
#undef FRAGA128
#undef FRAGB128
#undef READA128
#undef READB128
#undef MFMA8
#undef HALF128
}

// ---------------------------------------------------------------------------
// Transpose V with PV-fragment key permutation:
//   vtb position (within each 64-key tile) p holds key c', where
//     p(c') = (c'&32) | ((c'>>2)&3)<<3 | ((c'>>4)&1)<<2 | (c'&3)   (bijective)
// This makes the PV A-operand (P fragments) LANE-LOCAL in the attn kernel.
// ---------------------------------------------------------------------------
__global__ __launch_bounds__(256) void vtranspose(const __hip_bfloat16* __restrict__ qkvb,
                                                  __hip_bfloat16* __restrict__ vtb) {
    __shared__ __align__(16) __hip_bfloat16 st[64][LDK];
    const int bh = blockIdx.x >> 5;
    const int tt = blockIdx.x & 31;
    const int b = bh >> 4;
    const int h = bh & 15;
    const int tid = threadIdx.x;
    const int row = tid >> 3;
    const int a = tid & 7;
    const int col8 = a * 8;

#pragma unroll
    for (int pass = 0; pass < 2; ++pass) {
        int t = pass * 32 + row;
        *(bf16x8*)(&st[t][col8]) =
            *(const bf16x8*)(qkvb + ((size_t)(b * TT + tt * 64 + t)) * C3 + 2 * CC + h * HD + col8);
    }
    __syncthreads();
    const int h32 = (a >> 2) & 1;
    const int m4  = (a >> 1) & 1;
    const int p0 = h32 * 32 + ((2 * a) & 3) * 8 + m4 * 4;
    const int p1 = h32 * 32 + ((2 * a + 1) & 3) * 8 + m4 * 4;
#pragma unroll
    for (int pass = 0; pass < 2; ++pass) {
        int d = pass * 32 + row;
        __align__(16) __hip_bfloat16 tmp[8];
#pragma unroll
        for (int j = 0; j < 8; ++j) tmp[j] = st[col8 + j][d];
        __hip_bfloat16* dst = vtb + ((size_t)bh * HD + d) * TT + tt * 64;
        *(bf16x4*)(dst + p0) = *(const bf16x4*)&tmp[0];
        *(bf16x4*)(dst + p1) = *(const bf16x4*)&tmp[4];
    }
}

// ---------------------------------------------------------------------------
// MFMA flash attention v9 (causal): register-P via permuted V + XCD remap.
// (unchanged from round 5 — verified)
// ---------------------------------------------------------------------------
__global__ __launch_bounds__(256) void attn_mfma9(const __hip_bfloat16* __restrict__ qkvb,
                                                  const __hip_bfloat16* __restrict__ vtb,
                                                  __hip_bfloat16* __restrict__ y) {
    __shared__ __align__(16) __hip_bfloat16 Kb[3][64 * 64];   // [key][dim], XOR-swizzled
    __shared__ __align__(16) __hip_bfloat16 Vb[3][64 * 64];   // [dim][key], XOR-swizzled

    const int tid = threadIdx.x;
    const int w = tid >> 6;
    const int lane = tid & 63;
    const int l16 = lane & 15;
    const int quad = lane >> 4;
    const int swz = l16 & 7;

    const int rb = blockIdx.x;
    const int lb = (rb & 7) * 64 + (rb >> 3);   // XCD-chunked bijective remap (512 = 8*64)
    const int bh = lb >> 3;
    const int pr = lb & 7;
    const int b = bh >> 4;
    const int h = bh & 15;

    const int sr = (lane >> 3) & 7;
    const int sc = lane & 7;
    const int klog = (sc ^ sr) * 8;

    const __hip_bfloat16* kbase = qkvb + (size_t)b * TT * C3 + CC + h * HD + klog;
    const __hip_bfloat16* vbase = vtb + (size_t)bh * HD * TT + klog;

#define ATTN_STAGE(t, bidx) do {                                                  \
    _Pragma("unroll")                                                             \
    for (int half = 0; half < 2; ++half) {                                        \
        int kr = w * 16 + half * 8 + sr;                                          \
        gload_lds16(kbase + (size_t)((t) * 64 + kr) * C3,                         \
                    Kb[bidx] + (w * 16 + half * 8) * 64);                         \
        gload_lds16(vbase + (size_t)kr * TT + (t) * 64,                           \
                    Vb[bidx] + (w * 16 + half * 8) * 64);                         \
    }                                                                             \
} while (0)

#pragma unroll
    for (int seg = 0; seg < 2; ++seg) {
        const int qblk = (seg == 0) ? (15 - pr) : pr;
        const int qb = qblk * 128;
        const int jtmax = 2 * qblk + 1;
        const int qn0 = qb + w * 32;
        const int qn1 = qn0 + 16;

        // Q B-frags (B[k=dim][n=query]), rope'd + exp2-scaled already
        bf16x8 qf[2][2];
#pragma unroll
        for (int qt = 0; qt < 2; ++qt) {
            const __hip_bfloat16* qp = qkvb + (size_t)(b * TT + qn0 + qt * 16 + l16) * C3 + h * HD;
            qf[qt][0] = *(const bf16x8*)(qp + quad * 8);
            qf[qt][1] = *(const bf16x8*)(qp + 32 + quad * 8);
        }

        f32x4 O[2][4] = {};
        float l_q[2] = {0.f, 0.f};                // per-quad partial; reduced in epilogue

        __syncthreads();   // full drain: buffers from previous segment consumed
        // prologue: stage tiles 0 and 1 into buffers 0 and 1 (4 vm-events each/wave)
        ATTN_STAGE(0, 0);
        ATTN_STAGE(1, 1);

        int bcur = 0;      // LDS buffer holding tile jt
        for (int jt = 0; jt <= jtmax; ++jt) {
            // own 4 loads of tile jt complete; tile jt+1's 4 may stay in flight
            if (jt < jtmax) { WAIT_VM4(); } else { WAIT_VM0(); }
            BAR(); SB0();   // raw barrier, no counter drain

            if (jt + 2 <= jtmax) {
                const int bs = (bcur >= 1) ? (bcur - 1) : 2;   // (bcur+2)%3
                ATTN_STAGE(jt + 2, bs);
            }

            const __hip_bfloat16* Kp = Kb[bcur];
            const __hip_bfloat16* Vp = Vb[bcur];

            const bool sk0 = (jt * 64 > qn0 + 15);
            const bool sk1 = (jt * 64 > qn1 + 15);

            if (!sk1) {
                // ---- S^T = K * Q^T (exp2 domain, zero-init) ----
                f32x4 St[2][4] = {};
                __builtin_amdgcn_s_setprio(1);
#pragma unroll
                for (int ks = 0; ks < 2; ++ks) {
#pragma unroll
                    for (int mt = 0; mt < 4; ++mt) {
                        bf16x8 kf = *(const bf16x8*)(Kp + (mt * 16 + l16) * 64 +
                                                     ((ks * 4 + quad) ^ swz) * 8);
                        St[0][mt] = __builtin_amdgcn_mfma_f32_16x16x32_bf16(kf, qf[0][ks], St[0][mt], 0, 0, 0);
                        St[1][mt] = __builtin_amdgcn_mfma_f32_16x16x32_bf16(kf, qf[1][ks], St[1][mt], 0, 0, 0);
                    }
                }
                __builtin_amdgcn_s_setprio(0);

                // ---- V-frags (shared by both qtiles); permuted key order ----
                bf16x8 vf[4][2];
#pragma unroll
                for (int dt = 0; dt < 4; ++dt) {
                    vf[dt][0] = *(const bf16x8*)(Vp + (dt * 16 + l16) * 64 + ((quad) ^ swz) * 8);
                    vf[dt][1] = *(const bf16x8*)(Vp + (dt * 16 + l16) * 64 + ((4 + quad) ^ swz) * 8);
                }

                // ---- per-qtile: mask, exp2, REGISTER pack, PV (no LDS) ----
#pragma unroll
                for (int qt = 0; qt < 2; ++qt) {
                    const bool skq = qt == 0 ? sk0 : sk1;
                    if (skq) continue;
                    const int qn = qt == 0 ? qn0 : qn1;
                    if (jt * 64 + 63 > qn) {        // diagonal tile: causal mask
#pragma unroll
                        for (int mt = 0; mt < 4; ++mt) {
#pragma unroll
                            for (int r = 0; r < 4; ++r) {
                                int key = jt * 64 + mt * 16 + quad * 4 + r;
                                if (key > qn + l16) St[qt][mt][r] = -__builtin_inff();
                            }
                        }
                    }
                    float sum = 0.f;
                    union { bf16x8 v; __hip_bfloat162 hh[4]; } pk0, pk1;
#pragma unroll
                    for (int mt = 0; mt < 4; ++mt) {
                        float e0 = exp2f(St[qt][mt][0]);
                        float e1 = exp2f(St[qt][mt][1]);
                        float e2 = exp2f(St[qt][mt][2]);
                        float e3 = exp2f(St[qt][mt][3]);
                        sum += (e0 + e1) + (e2 + e3);
                        __hip_bfloat162 lo = __float22bfloat162_rn(make_float2(e0, e1));
                        __hip_bfloat162 hi = __float22bfloat162_rn(make_float2(e2, e3));
                        if (mt < 2) { pk0.hh[mt * 2] = lo; pk0.hh[mt * 2 + 1] = hi; }
                        else        { pk1.hh[(mt - 2) * 2] = lo; pk1.hh[(mt - 2) * 2 + 1] = hi; }
                    }
                    l_q[qt] += sum;

                    __builtin_amdgcn_s_setprio(1);
#pragma unroll
                    for (int dt = 0; dt < 4; ++dt) {
                        O[qt][dt] = __builtin_amdgcn_mfma_f32_16x16x32_bf16(pk0.v, vf[dt][0], O[qt][dt], 0, 0, 0);
                        O[qt][dt] = __builtin_amdgcn_mfma_f32_16x16x32_bf16(pk1.v, vf[dt][1], O[qt][dt], 0, 0, 0);
                    }
                    __builtin_amdgcn_s_setprio(0);
                }
            }

            bcur = (bcur == 2) ? 0 : bcur + 1;
        }

        // ---- epilogue: reduce l across quads, normalize, store ----
#pragma unroll
        for (int qt = 0; qt < 2; ++qt) {
            float l2 = l_q[qt];
            l2 += __shfl_xor(l2, 16);
            l2 += __shfl_xor(l2, 32);
            float lO[4];
#pragma unroll
            for (int r = 0; r < 4; ++r) lO[r] = 1.0f / __shfl(l2, quad * 4 + r);
            const int qbase = qn0 + qt * 16 + quad * 4;
#pragma unroll
            for (int dt = 0; dt < 4; ++dt) {
#pragma unroll
                for (int r = 0; r < 4; ++r) {
                    y[(size_t)(b * TT + qbase + r) * CC + h * HD + dt * 16 + l16] =
                        __float2bfloat16(O[qt][dt][r] * lO[r]);
                }
            }
        }
    }
#undef ATTN_STAGE
}

// ---------------------------------------------------------------------------
extern "C" void kernel_launch(void* const* d_in, const int* in_sizes, int n_in,
                              void* d_out, int out_size, void* d_ws, size_t ws_size,
                              hipStream_t stream) {
    const float* x      = (const float*)d_in[0];   // (B,T,C)
    const float* W_attn = (const float*)d_in[1];   // (C, 3C)
    const float* W_proj = (const float*)d_in[2];   // (C, C)
    float* out = (float*)d_out;                    // (B,T,C)

    const size_t NBT = (size_t)BB * TT;            // 8192
    __hip_bfloat16* xb   = (__hip_bfloat16*)d_ws;           // B*T*C (reused as yb)
    __hip_bfloat16* qkvb = xb + NBT * CC;                   // B*T*3C
    __hip_bfloat16* vtb  = qkvb + NBT * C3;                 // B*H*64*T
    __hip_bfloat16* Wab  = vtb + NBT * CC;                  // 3C*C  [N][K]
    __hip_bfloat16* Wpb  = Wab + (size_t)CC * C3;           // C*C   [N][K]
    float2* tab          = (float2*)(Wpb + (size_t)CC * CC); // T*32 float2 = 512 KB
    __hip_bfloat16* yb   = xb;                              // reuse after qkv GEMM

    const int M = BB * TT;   // 8192

    rope_tables<<<dim3(TT * 32 / 256), 256, 0, stream>>>(tab);
    cast_bf16x8<<<dim3((int)(NBT * CC / 2048)), 256, 0, stream>>>(x, xb);
    wtrans<<<dim3(C3 / 64, CC / 64), 256, 0, stream>>>(W_attn, Wab, CC, C3);
    wtrans<<<dim3(CC / 64, CC / 64), 256, 0, stream>>>(W_proj, Wpb, CC, CC);

    // 1) qkv = x @ W_attn with fused table-RoPE epilogue (8-phase 256^2, XCD remap)
    gemm256_qkv_rope<<<dim3(384), 512, 0, stream>>>(xb, Wab, tab, qkvb, M, C3, CC);

    // 2) transpose V (with PV-fragment key permutation)
    vtranspose<<<dim3(BB * NH * (TT / 64)), 256, 0, stream>>>(qkvb, vtb);

    // 3) MFMA flash attention v9 (register-P + XCD remap) -> yb (bf16)
    attn_mfma9<<<dim3(BB * NH * 8), 256, 0, stream>>>(qkvb, vtb, yb);

    // 4) out = yb @ W_proj  (8-phase 128x256, 256 blocks = one full round, fp32 out)
    gemm128_f32<<<dim3(256), 512, 0, stream>>>(yb, Wpb, out, M, CC, CC);
}

// Round 7
// 251.787 us; speedup vs baseline: 1.3272x; 1.0799x over previous
//
#include <hip/hip_runtime.h>
#include <hip/hip_bf16.h>
#include <math.h>

// Problem constants
#define BB 4
#define TT 2048
#define CC 1024
#define NH 16
#define HD 64
#define C3 3072
#define LDK 72   // padded LDS row stride (bf16 elems) - vtranspose only

// exp2-domain query scale: 0.125 * log2(e)
#define QSCALE 0.18033688011112042f

typedef __attribute__((ext_vector_type(8))) short bf16x8;
typedef __attribute__((ext_vector_type(4))) short bf16x4;
typedef __attribute__((ext_vector_type(4))) float f32x4;

// async global->LDS, 16 B per lane; LDS dest = wave-uniform base + lane*16
__device__ __forceinline__ void gload_lds16(const __hip_bfloat16* g, __hip_bfloat16* s) {
    __builtin_amdgcn_global_load_lds((const __attribute__((address_space(1))) void*)g,
                                     (__attribute__((address_space(3))) void*)s, 16, 0, 0);
}

// ---------------------------------------------------------------------------
// RoPE tables: tab[t*32 + p] = (cos, sin); the only sincosf call site.
// ---------------------------------------------------------------------------
__global__ __launch_bounds__(256) void rope_tables(float2* __restrict__ tab) {
    int idx = blockIdx.x * 256 + threadIdx.x;   // 0..65535
    int t = idx >> 5;
    int p = idx & 31;
    float invf = exp2f((float)p * (-13.287712379549449f / 32.0f));  // 10000^(-p/32)
    float ang = (float)t * invf;
    float s, c;
    sincosf(ang, &s, &c);
    tab[idx] = make_float2(c, s);
}

// ---------------------------------------------------------------------------
// cast fp32 -> bf16, 8 elements/thread
// ---------------------------------------------------------------------------
__global__ __launch_bounds__(256) void cast_bf16x8(const float* __restrict__ X,
                                                   __hip_bfloat16* __restrict__ Y) {
    size_t i = ((size_t)blockIdx.x * 256 + threadIdx.x) * 8;
    float4 a = *(const float4*)(X + i);
    float4 b = *(const float4*)(X + i + 4);
    __align__(16) __hip_bfloat16 tmp[8];
    tmp[0] = __float2bfloat16(a.x);
    tmp[1] = __float2bfloat16(a.y);
    tmp[2] = __float2bfloat16(a.z);
    tmp[3] = __float2bfloat16(a.w);
    tmp[4] = __float2bfloat16(b.x);
    tmp[5] = __float2bfloat16(b.y);
    tmp[6] = __float2bfloat16(b.z);
    tmp[7] = __float2bfloat16(b.w);
    *(bf16x8*)(Y + i) = *(bf16x8*)tmp;
}

// ---------------------------------------------------------------------------
// W[K][N] fp32  ->  Wt[N][K] bf16   (64x64 tiles via LDS)
// ---------------------------------------------------------------------------
__global__ __launch_bounds__(256) void wtrans(const float* __restrict__ W,
                                              __hip_bfloat16* __restrict__ Wt,
                                              int K, int N) {
    __shared__ float st[64][65];
    const int n0 = blockIdx.x * 64;
    const int k0 = blockIdx.y * 64;
    const int tid = threadIdx.x;
    const int r = tid >> 4;
    const int c4 = (tid & 15) * 4;
#pragma unroll
    for (int p = 0; p < 4; ++p) {
        int k = p * 16 + r;
        float4 v = *(const float4*)(W + (size_t)(k0 + k) * N + n0 + c4);
        st[c4 + 0][k] = v.x;
        st[c4 + 1][k] = v.y;
        st[c4 + 2][k] = v.z;
        st[c4 + 3][k] = v.w;
    }
    __syncthreads();
    const int rr = tid >> 3;
    const int cc = (tid & 7) * 8;
#pragma unroll
    for (int p = 0; p < 2; ++p) {
        int n = p * 32 + rr;
        __align__(16) __hip_bfloat16 tmp[8];
#pragma unroll
        for (int j = 0; j < 8; ++j) tmp[j] = __float2bfloat16(st[n][cc + j]);
        *(bf16x8*)(Wt + (size_t)(n0 + n) * K + k0 + cc) = *(bf16x8*)tmp;
    }
}

// ---------------------------------------------------------------------------
// 256x256 8-phase GEMM core (T2 swizzle + T3/T4 counted vmcnt + T5 setprio).
// bm0/bn0 must be defined by the caller (enables XCD-chunked remap).
// ---------------------------------------------------------------------------
#define CA0 0
#define CA1 1
#define CB0 2
#define CB1 3

#define BAR() __builtin_amdgcn_s_barrier()
#define SB0() __builtin_amdgcn_sched_barrier(0)
#define WAIT_LGKM0() do { asm volatile("s_waitcnt lgkmcnt(0)" ::: "memory"); SB0(); } while (0)
#define WAIT_VM4()   do { asm volatile("s_waitcnt vmcnt(4)" ::: "memory");  SB0(); } while (0)
#define WAIT_VM3()   do { asm volatile("s_waitcnt vmcnt(3)" ::: "memory");  SB0(); } while (0)
#define WAIT_VM0()   do { asm volatile("s_waitcnt vmcnt(0)" ::: "memory");  SB0(); } while (0)

#define CLAMP_TS(x) ((x) < NTILE ? (x) : (x) - 2)

// wave w stages subtile-row w (16 rows) of the chunk: 2 x 1KiB wave-calls
#define STAGE(gbase, h, ts, buf, cid) do {                                            \
    const __hip_bfloat16* _s = (gbase) + (size_t)((h) * 128 + w * 16) * K + (ts) * 64; \
    __hip_bfloat16* _d = &lds[buf][cid][w * 1024];                                    \
    gload_lds16(_s, _d);                                                              \
    gload_lds16(_s + 32, _d + 512);                                                   \
} while (0)

#define FRAGP(buf, cid, rowsub, ks)                                                   \
    ((const bf16x8*)((const char*)&lds[buf][cid][0] +                                 \
        (((rowsub) * 2 + (ks)) << 10) + (l16 << 6) + swzoff))

#define READ_A(buf, mi) do {                                                          \
    _Pragma("unroll") for (int _m = 0; _m < 4; ++_m)                                  \
    _Pragma("unroll") for (int _k = 0; _k < 2; ++_k)                                  \
        af[_m][_k] = *FRAGP(buf, wm, (mi) * 4 + _m, _k);                              \
} while (0)

#define READ_B(buf, ni) do {                                                          \
    _Pragma("unroll") for (int _n = 0; _n < 2; ++_n)                                  \
    _Pragma("unroll") for (int _k = 0; _k < 2; ++_k)                                  \
        bfr[(ni) * 2 + _n][_k] =                                                      \
            *FRAGP(buf, 2 + (wn >> 1), (wn & 1) * 4 + (ni) * 2 + _n, _k);             \
} while (0)

#define MFMA_Q(mb, nb) do {                                                           \
    __builtin_amdgcn_s_setprio(1);                                                    \
    _Pragma("unroll") for (int _m = 0; _m < 4; ++_m)                                  \
    _Pragma("unroll") for (int _n = 0; _n < 2; ++_n)                                  \
    _Pragma("unroll") for (int _k = 0; _k < 2; ++_k)                                  \
        acc[(mb) * 4 + _m][(nb) * 2 + _n] = __builtin_amdgcn_mfma_f32_16x16x32_bf16(  \
            af[_m][_k], bfr[(nb) * 2 + _n][_k], acc[(mb) * 4 + _m][(nb) * 2 + _n],    \
            0, 0, 0);                                                                 \
    __builtin_amdgcn_s_setprio(0);                                                    \
} while (0)

#define HALF_ITER(BUF, T12, B12, T34, B34) do {                                       \
    /* phase A: Q(0,0) */                                                             \
    READ_A(BUF, 0);                                                                   \
    READ_B(BUF, 0);                                                                   \
    STAGE(Bb, 1, CLAMP_TS(T12), B12, CB1);                                            \
    BAR(); WAIT_LGKM0();                                                              \
    MFMA_Q(0, 0);                                                                     \
    BAR();                                                                            \
    /* phase B: Q(0,1) */                                                             \
    READ_B(BUF, 1);                                                                   \
    STAGE(Ab, 1, CLAMP_TS(T12), B12, CA1);                                            \
    BAR(); WAIT_LGKM0();                                                              \
    MFMA_Q(0, 1);                                                                     \
    BAR();                                                                            \
    /* phase C: Q(1,0) */                                                             \
    READ_A(BUF, 1);                                                                   \
    STAGE(Bb, 0, CLAMP_TS(T34), B34, CB0);                                            \
    BAR(); WAIT_LGKM0();                                                              \
    MFMA_Q(1, 0);                                                                     \
    BAR();                                                                            \
    /* phase D: Q(1,1) */                                                             \
    STAGE(Ab, 0, CLAMP_TS(T34), B34, CA0);                                            \
    BAR(); WAIT_LGKM0();                                                              \
    MFMA_Q(1, 1);                                                                     \
    WAIT_VM4();                                                                       \
    BAR(); SB0();                                                                     \
} while (0)

#define GEMM256_BODY                                                                  \
    __shared__ __align__(16) __hip_bfloat16 lds[2][4][8192]; /* 128 KiB */            \
    const int tid = threadIdx.x;                                                      \
    const int w = tid >> 6;                                                           \
    const int lane = tid & 63;                                                        \
    const int l16 = lane & 15;                                                        \
    const int quad = lane >> 4;                                                       \
    const int wm = w >> 2;                                                            \
    const int wn = w & 3;                                                             \
    const int swzoff = ((quad * 8) ^ ((l16 & 8) << 1)) << 1;                          \
    const int NTILE = K >> 6;                                                         \
    const size_t laneOff = (size_t)(lane >> 2) * K +                                  \
                           (((lane & 3) * 8) ^ ((lane >> 5) << 4));                   \
    const __hip_bfloat16* Ab = A + (size_t)bm0 * K + laneOff;                         \
    const __hip_bfloat16* Bb = Bt + (size_t)bn0 * K + laneOff;                        \
    f32x4 acc[8][4] = {};                                                             \
    /* prologue: tile0 fully + tile1's CB0/CA0 (matches steady chronology) */         \
    STAGE(Bb, 0, 0, 0, CB0);                                                          \
    STAGE(Ab, 0, 0, 0, CA0);                                                          \
    STAGE(Bb, 1, 0, 0, CB1);                                                          \
    STAGE(Ab, 1, 0, 0, CA1);                                                          \
    STAGE(Bb, 0, 1, 1, CB0);                                                          \
    STAGE(Ab, 0, 1, 1, CA0);                                                          \
    WAIT_VM4();                                                                       \
    BAR(); SB0();                                                                     \
    for (int it = 0; it < NTILE / 2; ++it) {                                          \
        const int t = it * 2;                                                         \
        bf16x8 af[4][2], bfr[4][2];                                                   \
        HALF_ITER(0, t + 1, 1, t + 2, 0);                                             \
        HALF_ITER(1, t + 2, 0, t + 3, 1);                                             \
    }

// ---------------------------------------------------------------------------
// qkv = x @ W_attn with fused interleaved RoPE epilogue (8-phase 256^2 core)
// 1-D grid of 384 blocks, XCD-chunked remap (q = 48).
// ---------------------------------------------------------------------------
__global__ __launch_bounds__(512) void gemm256_qkv_rope(const __hip_bfloat16* __restrict__ A,
                                                        const __hip_bfloat16* __restrict__ Bt,
                                                        const float2* __restrict__ tab,
                                                        __hip_bfloat16* __restrict__ C,
                                                        int M, int N, int K) {
    const int lin = blockIdx.x;                  // 0..383
    const int nl = (lin & 7) * 48 + (lin >> 3);  // bijective (384 = 8*48)
    const int bn0 = (nl % 12) * 256;
    const int bm0 = (nl / 12) * 256;
    GEMM256_BODY

    if (bn0 < 2048) {
        const float qsc = (bn0 < 1024) ? QSCALE : 1.0f;
        const float sgn = (l16 & 1) ? 1.0f : -1.0f;
#pragma unroll
        for (int mt = 0; mt < 8; ++mt) {
            int row = bm0 + wm * 128 + mt * 16 + quad * 4;
#pragma unroll
            for (int nt = 0; nt < 4; ++nt) {
                int col = bn0 + wn * 64 + nt * 16 + l16;
                int p2 = nt * 8 + (l16 >> 1);
#pragma unroll
                for (int r = 0; r < 4; ++r) {
                    float own = acc[mt][nt][r];
                    float part = __shfl_xor(own, 1);
                    int trow = (row + r) & (TT - 1);
                    float2 cs = tab[(trow << 5) + p2];
                    float res = (own * cs.x + sgn * part * cs.y) * qsc;
                    C[(size_t)(row + r) * N + col] = __float2bfloat16(res);
                }
            }
        }
    } else {
#pragma unroll
        for (int mt = 0; mt < 8; ++mt) {
            int row = bm0 + wm * 128 + mt * 16 + quad * 4;
#pragma unroll
            for (int nt = 0; nt < 4; ++nt) {
                int col = bn0 + wn * 64 + nt * 16 + l16;
#pragma unroll
                for (int r = 0; r < 4; ++r)
                    C[(size_t)(row + r) * N + col] = __float2bfloat16(acc[mt][nt][r]);
            }
        }
    }
}

// ---------------------------------------------------------------------------
// out-proj GEMM: 128x256 tile, 8-phase schedule, fp32 store. 256 blocks =
// one full scheduling round. (unchanged — verified round 6)
// ---------------------------------------------------------------------------
__global__ __launch_bounds__(512) void gemm128_f32(const __hip_bfloat16* __restrict__ A,
                                                   const __hip_bfloat16* __restrict__ Bt,
                                                   float* __restrict__ C,
                                                   int M, int N, int K) {
    __shared__ __align__(16) __hip_bfloat16 lds[2][24576];  // CA0@0, CA1@4096, CB0@8192, CB1@16384 (elems)
    const int tid = threadIdx.x;
    const int w = tid >> 6;
    const int lane = tid & 63;
    const int l16 = lane & 15;
    const int quad = lane >> 4;
    const int wm = w >> 2;          // 0..1 -> M rows [wm*64, +64)
    const int wn = w & 3;           // 0..3 -> N cols [wn*64, +64)
    const int swzoff = ((quad * 8) ^ ((l16 & 8) << 1)) << 1;
    const int lin = blockIdx.x;                  // 0..255
    const int nl = (lin & 7) * 32 + (lin >> 3);  // bijective (256 = 8*32)
    const int bn0 = (nl & 3) * 256;
    const int bm0 = (nl >> 2) * 128;
    const int NTILE = K >> 6;
    const int aswz = ((lane & 3) * 8) ^ ((lane >> 5) << 4);
    const size_t laneOff = (size_t)(lane >> 2) * K + aswz;
    const __hip_bfloat16* Ab = A + (size_t)bm0 * K;          // per-call rows
    const __hip_bfloat16* Bb = Bt + (size_t)bn0 * K + laneOff;
    f32x4 acc[4][4] = {};

#define STAGE_A128(h, ts, buf) do {                                                   \
    const __hip_bfloat16* _s = Ab + (size_t)((h) * 64 + (w & 3) * 16 + (lane >> 2)) * K \
                               + (ts) * 64 + (w >> 2) * 32 + aswz;                    \
    gload_lds16(_s, &lds[buf][(h) * 4096 + ((w & 3) * 2 + (w >> 2)) * 512]);          \
} while (0)

#define STAGE_B128(h, ts, buf) do {                                                   \
    const __hip_bfloat16* _s = Bb + (size_t)((h) * 128 + w * 16) * K + (ts) * 64;     \
    __hip_bfloat16* _d = &lds[buf][8192 + (h) * 8192 + w * 1024];                     \
    gload_lds16(_s, _d);                                                              \
    gload_lds16(_s + 32, _d + 512);                                                   \
} while (0)

#define FRAGA128(buf, m_, ks)                                                         \
    ((const bf16x8*)((const char*)&lds[buf][wm * 4096] +                              \
        ((((m_) * 2 + (ks)) << 10) + (l16 << 6) + swzoff)))
#define FRAGB128(buf, n_, ks)                                                         \
    ((const bf16x8*)((const char*)&lds[buf][8192 + (wn >> 1) * 8192] +                \
        (((((wn & 1) * 4 + (n_)) * 2 + (ks)) << 10) + (l16 << 6) + swzoff)))

#define READA128(buf, mi) do {                                                        \
    _Pragma("unroll") for (int _m = 0; _m < 2; ++_m)                                  \
    _Pragma("unroll") for (int _k = 0; _k < 2; ++_k)                                  \
        af[(mi) * 2 + _m][_k] = *FRAGA128(buf, (mi) * 2 + _m, _k);                    \
} while (0)

#define READB128(buf, ni) do {                                                        \
    _Pragma("unroll") for (int _n = 0; _n < 2; ++_n)                                  \
    _Pragma("unroll") for (int _k = 0; _k < 2; ++_k)                                  \
        bfr[(ni) * 2 + _n][_k] = *FRAGB128(buf, (ni) * 2 + _n, _k);                   \
} while (0)

#define MFMA8(mb, nb) do {                                                            \
    __builtin_amdgcn_s_setprio(1);                                                    \
    _Pragma("unroll") for (int _m = 0; _m < 2; ++_m)                                  \
    _Pragma("unroll") for (int _n = 0; _n < 2; ++_n)                                  \
    _Pragma("unroll") for (int _k = 0; _k < 2; ++_k)                                  \
        acc[(mb) * 2 + _m][(nb) * 2 + _n] = __builtin_amdgcn_mfma_f32_16x16x32_bf16(  \
            af[(mb) * 2 + _m][_k], bfr[(nb) * 2 + _n][_k],                            \
            acc[(mb) * 2 + _m][(nb) * 2 + _n], 0, 0, 0);                              \
    __builtin_amdgcn_s_setprio(0);                                                    \
} while (0)

#define HALF128(BUF, T12, B12, T34, B34) do {                                         \
    READA128(BUF, 0);                                                                 \
    READB128(BUF, 0);                                                                 \
    STAGE_B128(1, CLAMP_TS(T12), B12);                                                \
    BAR(); WAIT_LGKM0();                                                              \
    MFMA8(0, 0);                                                                      \
    BAR();                                                                            \
    READB128(BUF, 1);                                                                 \
    STAGE_A128(1, CLAMP_TS(T12), B12);                                                \
    BAR(); WAIT_LGKM0();                                                              \
    MFMA8(0, 1);                                                                      \
    BAR();                                                                            \
    READA128(BUF, 1);                                                                 \
    STAGE_B128(0, CLAMP_TS(T34), B34);                                                \
    BAR(); WAIT_LGKM0();                                                              \
    MFMA8(1, 0);                                                                      \
    BAR();                                                                            \
    STAGE_A128(0, CLAMP_TS(T34), B34);                                                \
    BAR(); WAIT_LGKM0();                                                              \
    MFMA8(1, 1);                                                                      \
    WAIT_VM3();                                                                       \
    BAR(); SB0();                                                                     \
} while (0)

    // prologue: tile0 fully + tile1's CB0/CA0 (9 events; wait(3) retires tile0's 6)
    STAGE_B128(0, 0, 0);
    STAGE_A128(0, 0, 0);
    STAGE_B128(1, 0, 0);
    STAGE_A128(1, 0, 0);
    STAGE_B128(0, 1, 1);
    STAGE_A128(0, 1, 1);
    WAIT_VM3();
    BAR(); SB0();
    for (int it = 0; it < NTILE / 2; ++it) {
        const int t = it * 2;
        bf16x8 af[4][2], bfr[4][2];
        HALF128(0, t + 1, 1, t + 2, 0);
        HALF128(1, t + 2, 0, t + 3, 1);
    }
    WAIT_VM0();   // drain tail re-stages before epilogue/endpgm

#pragma unroll
    for (int mt = 0; mt < 4; ++mt) {
        int row = bm0 + wm * 64 + mt * 16 + quad * 4;
#pragma unroll
        for (int nt = 0; nt < 4; ++nt) {
            int col = bn0 + wn * 64 + nt * 16 + l16;
#pragma unroll
            for (int r = 0; r < 4; ++r)
                C[(size_t)(row + r) * N + col] = acc[mt][nt][r];
        }
    }
#undef STAGE_A128
#undef STAGE_B128
#undef FRAGA128
#undef FRAGB128
#undef READA128
#undef READB128
#undef MFMA8
#undef HALF128
}

// ---------------------------------------------------------------------------
// Transpose V with PV-fragment key permutation (unchanged — verified)
// ---------------------------------------------------------------------------
__global__ __launch_bounds__(256) void vtranspose(const __hip_bfloat16* __restrict__ qkvb,
                                                  __hip_bfloat16* __restrict__ vtb) {
    __shared__ __align__(16) __hip_bfloat16 st[64][LDK];
    const int bh = blockIdx.x >> 5;
    const int tt = blockIdx.x & 31;
    const int b = bh >> 4;
    const int h = bh & 15;
    const int tid = threadIdx.x;
    const int row = tid >> 3;
    const int a = tid & 7;
    const int col8 = a * 8;

#pragma unroll
    for (int pass = 0; pass < 2; ++pass) {
        int t = pass * 32 + row;
        *(bf16x8*)(&st[t][col8]) =
            *(const bf16x8*)(qkvb + ((size_t)(b * TT + tt * 64 + t)) * C3 + 2 * CC + h * HD + col8);
    }
    __syncthreads();
    const int h32 = (a >> 2) & 1;
    const int m4  = (a >> 1) & 1;
    const int p0 = h32 * 32 + ((2 * a) & 3) * 8 + m4 * 4;
    const int p1 = h32 * 32 + ((2 * a + 1) & 3) * 8 + m4 * 4;
#pragma unroll
    for (int pass = 0; pass < 2; ++pass) {
        int d = pass * 32 + row;
        __align__(16) __hip_bfloat16 tmp[8];
#pragma unroll
        for (int j = 0; j < 8; ++j) tmp[j] = st[col8 + j][d];
        __hip_bfloat16* dst = vtb + ((size_t)bh * HD + d) * TT + tt * 64;
        *(bf16x4*)(dst + p0) = *(const bf16x4*)&tmp[0];
        *(bf16x4*)(dst + p1) = *(const bf16x4*)&tmp[4];
    }
}

// ---------------------------------------------------------------------------
// MFMA flash attention v10 (causal): v9 skeleton + VALU-cut softmax:
//   - raw v_exp_f32 via __builtin_amdgcn_exp2f (scores exp2-domain-bounded;
//     masked lanes are exactly -inf -> exp2 = 0). Bypasses ocml's ~5-inst
//     denorm-safe expansion.
//   - row-sum l on the MATRIX pipe: one MFMA pair per qtile against a
//     constant all-ones B-fragment. C-layout rows = queries (quad*4+r),
//     matching the O epilogue indexing -> epilogue shuffles removed too.
//     (Masked keys contribute e=0; ones-frag is permutation-invariant.)
// ---------------------------------------------------------------------------
__global__ __launch_bounds__(256) void attn_mfma10(const __hip_bfloat16* __restrict__ qkvb,
                                                   const __hip_bfloat16* __restrict__ vtb,
                                                   __hip_bfloat16* __restrict__ y) {
    __shared__ __align__(16) __hip_bfloat16 Kb[3][64 * 64];   // [key][dim], XOR-swizzled
    __shared__ __align__(16) __hip_bfloat16 Vb[3][64 * 64];   // [dim][key], XOR-swizzled

    const int tid = threadIdx.x;
    const int w = tid >> 6;
    const int lane = tid & 63;
    const int l16 = lane & 15;
    const int quad = lane >> 4;
    const int swz = l16 & 7;

    const int rb = blockIdx.x;
    const int lb = (rb & 7) * 64 + (rb >> 3);   // XCD-chunked bijective remap (512 = 8*64)
    const int bh = lb >> 3;
    const int pr = lb & 7;
    const int b = bh >> 4;
    const int h = bh & 15;

    const int sr = (lane >> 3) & 7;
    const int sc = lane & 7;
    const int klog = (sc ^ sr) * 8;

    // all-ones bf16 B-fragment (1.0 = 0x3F80)
    union { bf16x8 v; short s[8]; } onesu;
#pragma unroll
    for (int j = 0; j < 8; ++j) onesu.s[j] = (short)0x3F80;
    const bf16x8 onesv = onesu.v;

    const __hip_bfloat16* kbase = qkvb + (size_t)b * TT * C3 + CC + h * HD + klog;
    const __hip_bfloat16* vbase = vtb + (size_t)bh * HD * TT + klog;

#define ATTN_STAGE(t, bidx) do {                                                  \
    _Pragma("unroll")                                                             \
    for (int half = 0; half < 2; ++half) {                                        \
        int kr = w * 16 + half * 8 + sr;                                          \
        gload_lds16(kbase + (size_t)((t) * 64 + kr) * C3,                         \
                    Kb[bidx] + (w * 16 + half * 8) * 64);                         \
        gload_lds16(vbase + (size_t)kr * TT + (t) * 64,                           \
                    Vb[bidx] + (w * 16 + half * 8) * 64);                         \
    }                                                                             \
} while (0)

#pragma unroll
    for (int seg = 0; seg < 2; ++seg) {
        const int qblk = (seg == 0) ? (15 - pr) : pr;
        const int qb = qblk * 128;
        const int jtmax = 2 * qblk + 1;
        const int qn0 = qb + w * 32;
        const int qn1 = qn0 + 16;

        // Q B-frags (B[k=dim][n=query]), rope'd + exp2-scaled already
        bf16x8 qf[2][2];
#pragma unroll
        for (int qt = 0; qt < 2; ++qt) {
            const __hip_bfloat16* qp = qkvb + (size_t)(b * TT + qn0 + qt * 16 + l16) * C3 + h * HD;
            qf[qt][0] = *(const bf16x8*)(qp + quad * 8);
            qf[qt][1] = *(const bf16x8*)(qp + 32 + quad * 8);
        }

        f32x4 O[2][4] = {};
        f32x4 lacc[2] = {};   // row-sum accumulators: lacc[qt][r] = l for query qt*16+quad*4+r

        __syncthreads();   // full drain: buffers from previous segment consumed
        // prologue: stage tiles 0 and 1 into buffers 0 and 1 (4 vm-events each/wave)
        ATTN_STAGE(0, 0);
        ATTN_STAGE(1, 1);

        int bcur = 0;      // LDS buffer holding tile jt
        for (int jt = 0; jt <= jtmax; ++jt) {
            // own 4 loads of tile jt complete; tile jt+1's 4 may stay in flight
            if (jt < jtmax) { WAIT_VM4(); } else { WAIT_VM0(); }
            BAR(); SB0();   // raw barrier, no counter drain

            if (jt + 2 <= jtmax) {
                const int bs = (bcur >= 1) ? (bcur - 1) : 2;   // (bcur+2)%3
                ATTN_STAGE(jt + 2, bs);
            }

            const __hip_bfloat16* Kp = Kb[bcur];
            const __hip_bfloat16* Vp = Vb[bcur];

            const bool sk0 = (jt * 64 > qn0 + 15);
            const bool sk1 = (jt * 64 > qn1 + 15);

            if (!sk1) {
                // ---- S^T = K * Q^T (exp2 domain, zero-init) ----
                f32x4 St[2][4] = {};
                __builtin_amdgcn_s_setprio(1);
#pragma unroll
                for (int ks = 0; ks < 2; ++ks) {
#pragma unroll
                    for (int mt = 0; mt < 4; ++mt) {
                        bf16x8 kf = *(const bf16x8*)(Kp + (mt * 16 + l16) * 64 +
                                                     ((ks * 4 + quad) ^ swz) * 8);
                        St[0][mt] = __builtin_amdgcn_mfma_f32_16x16x32_bf16(kf, qf[0][ks], St[0][mt], 0, 0, 0);
                        St[1][mt] = __builtin_amdgcn_mfma_f32_16x16x32_bf16(kf, qf[1][ks], St[1][mt], 0, 0, 0);
                    }
                }
                __builtin_amdgcn_s_setprio(0);

                // ---- V-frags (shared by both qtiles); permuted key order ----
                bf16x8 vf[4][2];
#pragma unroll
                for (int dt = 0; dt < 4; ++dt) {
                    vf[dt][0] = *(const bf16x8*)(Vp + (dt * 16 + l16) * 64 + ((quad) ^ swz) * 8);
                    vf[dt][1] = *(const bf16x8*)(Vp + (dt * 16 + l16) * 64 + ((4 + quad) ^ swz) * 8);
                }

                // ---- per-qtile: mask, raw exp2, REGISTER pack, PV + l-MFMA ----
#pragma unroll
                for (int qt = 0; qt < 2; ++qt) {
                    const bool skq = qt == 0 ? sk0 : sk1;
                    if (skq) continue;
                    const int qn = qt == 0 ? qn0 : qn1;
                    if (jt * 64 + 63 > qn) {        // diagonal tile: causal mask
#pragma unroll
                        for (int mt = 0; mt < 4; ++mt) {
#pragma unroll
                            for (int r = 0; r < 4; ++r) {
                                int key = jt * 64 + mt * 16 + quad * 4 + r;
                                if (key > qn + l16) St[qt][mt][r] = -__builtin_inff();
                            }
                        }
                    }
                    union { bf16x8 v; __hip_bfloat162 hh[4]; } pk0, pk1;
#pragma unroll
                    for (int mt = 0; mt < 4; ++mt) {
                        float e0 = __builtin_amdgcn_exp2f(St[qt][mt][0]);
                        float e1 = __builtin_amdgcn_exp2f(St[qt][mt][1]);
                        float e2 = __builtin_amdgcn_exp2f(St[qt][mt][2]);
                        float e3 = __builtin_amdgcn_exp2f(St[qt][mt][3]);
                        __hip_bfloat162 lo = __float22bfloat162_rn(make_float2(e0, e1));
                        __hip_bfloat162 hi = __float22bfloat162_rn(make_float2(e2, e3));
                        if (mt < 2) { pk0.hh[mt * 2] = lo; pk0.hh[mt * 2 + 1] = hi; }
                        else        { pk1.hh[(mt - 2) * 2] = lo; pk1.hh[(mt - 2) * 2 + 1] = hi; }
                    }

                    __builtin_amdgcn_s_setprio(1);
#pragma unroll
                    for (int dt = 0; dt < 4; ++dt) {
                        O[qt][dt] = __builtin_amdgcn_mfma_f32_16x16x32_bf16(pk0.v, vf[dt][0], O[qt][dt], 0, 0, 0);
                        O[qt][dt] = __builtin_amdgcn_mfma_f32_16x16x32_bf16(pk1.v, vf[dt][1], O[qt][dt], 0, 0, 0);
                    }
                    // row-sum on the matrix pipe: l[q] += sum_k P[q][k]
                    lacc[qt] = __builtin_amdgcn_mfma_f32_16x16x32_bf16(pk0.v, onesv, lacc[qt], 0, 0, 0);
                    lacc[qt] = __builtin_amdgcn_mfma_f32_16x16x32_bf16(pk1.v, onesv, lacc[qt], 0, 0, 0);
                    __builtin_amdgcn_s_setprio(0);
                }
            }

            bcur = (bcur == 2) ? 0 : bcur + 1;
        }

        // ---- epilogue: normalize by lacc (already per-query), store ----
#pragma unroll
        for (int qt = 0; qt < 2; ++qt) {
            float lO[4];
#pragma unroll
            for (int r = 0; r < 4; ++r) lO[r] = 1.0f / lacc[qt][r];
            const int qbase = qn0 + qt * 16 + quad * 4;
#pragma unroll
            for (int dt = 0; dt < 4; ++dt) {
#pragma unroll
                for (int r = 0; r < 4; ++r) {
                    y[(size_t)(b * TT + qbase + r) * CC + h * HD + dt * 16 + l16] =
                        __float2bfloat16(O[qt][dt][r] * lO[r]);
                }
            }
        }
    }
#undef ATTN_STAGE
}

// ---------------------------------------------------------------------------
extern "C" void kernel_launch(void* const* d_in, const int* in_sizes, int n_in,
                              void* d_out, int out_size, void* d_ws, size_t ws_size,
                              hipStream_t stream) {
    const float* x      = (const float*)d_in[0];   // (B,T,C)
    const float* W_attn = (const float*)d_in[1];   // (C, 3C)
    const float* W_proj = (const float*)d_in[2];   // (C, C)
    float* out = (float*)d_out;                    // (B,T,C)

    const size_t NBT = (size_t)BB * TT;            // 8192
    __hip_bfloat16* xb   = (__hip_bfloat16*)d_ws;           // B*T*C (reused as yb)
    __hip_bfloat16* qkvb = xb + NBT * CC;                   // B*T*3C
    __hip_bfloat16* vtb  = qkvb + NBT * C3;                 // B*H*64*T
    __hip_bfloat16* Wab  = vtb + NBT * CC;                  // 3C*C  [N][K]
    __hip_bfloat16* Wpb  = Wab + (size_t)CC * C3;           // C*C   [N][K]
    float2* tab          = (float2*)(Wpb + (size_t)CC * CC); // T*32 float2 = 512 KB
    __hip_bfloat16* yb   = xb;                              // reuse after qkv GEMM

    const int M = BB * TT;   // 8192

    rope_tables<<<dim3(TT * 32 / 256), 256, 0, stream>>>(tab);
    cast_bf16x8<<<dim3((int)(NBT * CC / 2048)), 256, 0, stream>>>(x, xb);
    wtrans<<<dim3(C3 / 64, CC / 64), 256, 0, stream>>>(W_attn, Wab, CC, C3);
    wtrans<<<dim3(CC / 64, CC / 64), 256, 0, stream>>>(W_proj, Wpb, CC, CC);

    // 1) qkv = x @ W_attn with fused table-RoPE epilogue (8-phase 256^2, XCD remap)
    gemm256_qkv_rope<<<dim3(384), 512, 0, stream>>>(xb, Wab, tab, qkvb, M, C3, CC);

    // 2) transpose V (with PV-fragment key permutation)
    vtranspose<<<dim3(BB * NH * (TT / 64)), 256, 0, stream>>>(qkvb, vtb);

    // 3) MFMA flash attention v10 (raw exp2 + MFMA row-sum) -> yb (bf16)
    attn_mfma10<<<dim3(BB * NH * 8), 256, 0, stream>>>(qkvb, vtb, yb);

    // 4) out = yb @ W_proj  (8-phase 128x256, 256 blocks = one full round, fp32 out)
    gemm128_f32<<<dim3(256), 512, 0, stream>>>(yb, Wpb, out, M, CC, CC);
}